// Round 1
// baseline (1055.564 us; speedup 1.0000x reference)
//
#include <hip/hip_runtime.h>
#include <math.h>

#define D 64
#define S 64
#define BSZ 512
#define LTW 2016
#define ZROW 6112
#define OUT0_SIZE (BSZ * S * D)   // 2097152 floats
#define ZADJ_OFF  OUT0_SIZE

// ---------------------------------------------------------------------------
// k_xT: transpose x (512,64) -> xT (64,512) so main-kernel loads are coalesced
// ---------------------------------------------------------------------------
__global__ __launch_bounds__(256) void k_xT(const float* __restrict__ x,
                                            float* __restrict__ xT) {
    __shared__ float tile[64][65];
    const int bt = blockIdx.x;          // 8 tiles of 64 b's
    const int tid = threadIdx.x;
    const int r0 = tid >> 6, q = tid & 63;
#pragma unroll
    for (int rep = 0; rep < 16; ++rep) {
        int brow = rep * 4 + r0;
        tile[brow][q] = x[(bt * 64 + brow) * 64 + q];        // coalesced read
    }
    __syncthreads();
#pragma unroll
    for (int rep = 0; rep < 16; ++rep) {
        int irow = rep * 4 + r0;
        xT[irow * 512 + bt * 64 + q] = tile[q][irow];        // coalesced write
    }
}

// ---------------------------------------------------------------------------
// k_zadj: per s, build z_lt (strict lower-tri), z_p, then z_p^T @ z_lt @ z_p
// Writes z_adj (second output) directly into d_out + ZADJ_OFF.
// ---------------------------------------------------------------------------
__global__ __launch_bounds__(256) void k_zadj(const float* __restrict__ z,
                                              float* __restrict__ zadj) {
    __shared__ float zp[64 * 64];
    __shared__ float zlt[64 * 64];
    __shared__ float T[64 * 64];
    const int s = blockIdx.x;
    const int tid = threadIdx.x;
    const float* zs = z + (size_t)s * ZROW;

#pragma unroll
    for (int rep = 0; rep < 16; ++rep) {
        int idx = tid + rep * 256;
        zp[idx] = zs[LTW + idx];
        zlt[idx] = 0.0f;
    }
    __syncthreads();
    // scatter strict lower triangle: k -> (r,t), r(r-1)/2 <= k < r(r+1)/2
    for (int k = tid; k < LTW; k += 256) {
        float kf = (float)k;
        int r = (int)((1.0f + sqrtf(1.0f + 8.0f * kf)) * 0.5f);
        while (r * (r - 1) / 2 > k) --r;
        while ((r + 1) * r / 2 <= k) ++r;
        int t = k - r * (r - 1) / 2;
        zlt[r * 64 + t] = zs[k];
    }
    __syncthreads();
    // T = z_lt @ z_p : T[r][j] = sum_t zlt[r][t] * zp[t][j]
#pragma unroll
    for (int rep = 0; rep < 16; ++rep) {
        int idx = tid + rep * 256;
        int r = idx >> 6, j = idx & 63;
        float acc = 0.0f;
        for (int t = 0; t < 64; ++t)
            acc = fmaf(zlt[r * 64 + t], zp[t * 64 + j], acc);
        T[idx] = acc;
    }
    __syncthreads();
    // z_adj[i][j] = sum_r zp[r][i] * T[r][j]
#pragma unroll
    for (int rep = 0; rep < 16; ++rep) {
        int idx = tid + rep * 256;
        int i = idx >> 6, j = idx & 63;
        float acc = 0.0f;
        for (int r = 0; r < 64; ++r)
            acc = fmaf(zp[r * 64 + i], T[r * 64 + j], acc);
        zadj[(size_t)s * 4096 + idx] = acc;                  // coalesced
    }
}

// ---------------------------------------------------------------------------
// k_main: fused 4-layer per-channel MLP.
// Block = (c, s); 4 waves; lane = batch. Weights + z_adj column are
// wave-uniform -> scalar loads feeding v_fmac (SGPR operand), h/h1/h2 in VGPRs.
// ---------------------------------------------------------------------------
__global__ __launch_bounds__(256, 2) void k_main(
    const float* __restrict__ xsrc, int xi_s, int xb_s,
    const float* __restrict__ zadj,
    const float* __restrict__ W0, const float* __restrict__ B0,
    const float* __restrict__ W1, const float* __restrict__ B1,
    const float* __restrict__ W2, const float* __restrict__ B2,
    const float* __restrict__ W3, const float* __restrict__ B3,
    float* __restrict__ outp, int o_sS, int o_cS, int o_bS) {
    const int c = blockIdx.x;
    const int s = blockIdx.y;
    const int lane = threadIdx.x & 63;
    const int wave = __builtin_amdgcn_readfirstlane(threadIdx.x >> 6);

    const float* w0c = W0 + c * 2048;   // (32,64) row-major in i
    const float* w1c = W1 + c * 1024;   // (32,32)
    const float* w2c = W2 + c * 1024;
    const float* w3c = W3 + c * 32;
    const float* b0c = B0 + c * 32;
    const float* b1c = B1 + c * 32;
    const float* b2c = B2 + c * 32;
    const float b3v = B3[c];
    const float* zc = zadj + s * 4096 + c;   // element i at zc[i*64]

    float h[64], h1[32], h2[32];

#pragma unroll 1   // keep loop body within I$ (one iter ~ 4.2K FMAs)
    for (int bc = 0; bc < 2; ++bc) {
        const int b = wave * 128 + bc * 64 + lane;
        // h[i] = z_adj[s,i,c] * x[b,i]
#pragma unroll
        for (int i = 0; i < 64; ++i) {
            float xv = xsrc[i * xi_s + b * xb_s];
            h[i] = zc[i * 64] * xv;
        }
        // layer 0: 64 -> 32, relu
#pragma unroll
        for (int o = 0; o < 32; ++o) {
            float a = b0c[o];
#pragma unroll
            for (int i = 0; i < 64; ++i) a = fmaf(w0c[o * 64 + i], h[i], a);
            h1[o] = fmaxf(a, 0.0f);
        }
        // layer 1: 32 -> 32, relu
#pragma unroll
        for (int o = 0; o < 32; ++o) {
            float a = b1c[o];
#pragma unroll
            for (int j = 0; j < 32; ++j) a = fmaf(w1c[o * 32 + j], h1[j], a);
            h2[o] = fmaxf(a, 0.0f);
        }
        // layer 2: 32 -> 32, relu (write back into h1)
#pragma unroll
        for (int o = 0; o < 32; ++o) {
            float a = b2c[o];
#pragma unroll
            for (int j = 0; j < 32; ++j) a = fmaf(w2c[o * 32 + j], h2[j], a);
            h1[o] = fmaxf(a, 0.0f);
        }
        // layer 3: 32 -> 1
        float a = b3v;
#pragma unroll
        for (int j = 0; j < 32; ++j) a = fmaf(w3c[j], h1[j], a);
        outp[s * o_sS + c * o_cS + b * o_bS] = a;
    }
}

// ---------------------------------------------------------------------------
// k_outT: transpose outT (s,c,b) -> out (b,s,c)
// ---------------------------------------------------------------------------
__global__ __launch_bounds__(256) void k_outT(const float* __restrict__ outT,
                                              float* __restrict__ out) {
    __shared__ float tile[64][65];
    const int bt = blockIdx.x;   // 8 b-tiles
    const int s = blockIdx.y;    // 64
    const int tid = threadIdx.x;
    const int r0 = tid >> 6, q = tid & 63;
#pragma unroll
    for (int rep = 0; rep < 16; ++rep) {
        int crow = rep * 4 + r0;
        tile[crow][q] = outT[(s * 64 + crow) * 512 + bt * 64 + q];  // coalesced
    }
    __syncthreads();
#pragma unroll
    for (int rep = 0; rep < 16; ++rep) {
        int brow = rep * 4 + r0;
        out[(bt * 64 + brow) * 4096 + s * 64 + q] = tile[q][brow];  // coalesced
    }
}

extern "C" void kernel_launch(void* const* d_in, const int* in_sizes, int n_in,
                              void* d_out, int out_size, void* d_ws, size_t ws_size,
                              hipStream_t stream) {
    const float* x  = (const float*)d_in[0];
    const float* z  = (const float*)d_in[1];
    const float* W0 = (const float*)d_in[2];
    const float* B0 = (const float*)d_in[3];
    const float* W1 = (const float*)d_in[4];
    const float* B1 = (const float*)d_in[5];
    const float* W2 = (const float*)d_in[6];
    const float* B2 = (const float*)d_in[7];
    const float* W3 = (const float*)d_in[8];
    const float* B3 = (const float*)d_in[9];

    float* out  = (float*)d_out;
    float* zadj = out + ZADJ_OFF;

    // workspace layout: xT (131072 B) | outT (8388608 B) — degrade gracefully
    const size_t XT_BYTES = 64 * 512 * sizeof(float);
    const size_t OT_BYTES = (size_t)S * D * BSZ * sizeof(float);
    const bool has_xT = ws_size >= XT_BYTES;
    const bool has_oT = ws_size >= XT_BYTES + OT_BYTES;
    float* xT   = (float*)d_ws;
    float* outT = (float*)((char*)d_ws + XT_BYTES);

    hipLaunchKernelGGL(k_zadj, dim3(S), dim3(256), 0, stream, z, zadj);
    if (has_xT)
        hipLaunchKernelGGL(k_xT, dim3(8), dim3(256), 0, stream, x, xT);

    const float* xs = has_xT ? (const float*)xT : x;
    const int xi_s = has_xT ? 512 : 1;
    const int xb_s = has_xT ? 1 : 64;
    float* op = has_oT ? outT : out;
    const int o_sS = has_oT ? (64 * 512) : 64;
    const int o_cS = has_oT ? 512 : 1;
    const int o_bS = has_oT ? 1 : 4096;

    hipLaunchKernelGGL(k_main, dim3(D, S), dim3(256), 0, stream,
                       xs, xi_s, xb_s, zadj,
                       W0, B0, W1, B1, W2, B2, W3, B3,
                       op, o_sS, o_cS, o_bS);

    if (has_oT)
        hipLaunchKernelGGL(k_outT, dim3(8, S), dim3(256), 0, stream, outT, out);
}

// Round 2
// 311.334 us; speedup vs baseline: 3.3905x; 3.3905x over previous
//
#include <hip/hip_runtime.h>
#include <math.h>

#define D 64
#define S 64
#define BSZ 512
#define LTW 2016
#define ZROW 6112
#define OUT0_SIZE (BSZ * S * D)   // 2097152 floats
#define ZADJ_OFF  OUT0_SIZE

// ---------------------------------------------------------------------------
// k_xT: transpose x (512,64) -> xT (64,512) so main-kernel loads are coalesced
// ---------------------------------------------------------------------------
__global__ __launch_bounds__(256) void k_xT(const float* __restrict__ x,
                                            float* __restrict__ xT) {
    __shared__ float tile[64][65];
    const int bt = blockIdx.x;          // 8 tiles of 64 b's
    const int tid = threadIdx.x;
    const int r0 = tid >> 6, q = tid & 63;
#pragma unroll
    for (int rep = 0; rep < 16; ++rep) {
        int brow = rep * 4 + r0;
        tile[brow][q] = x[(bt * 64 + brow) * 64 + q];        // coalesced read
    }
    __syncthreads();
#pragma unroll
    for (int rep = 0; rep < 16; ++rep) {
        int irow = rep * 4 + r0;
        xT[irow * 512 + bt * 64 + q] = tile[q][irow];        // coalesced write
    }
}

// ---------------------------------------------------------------------------
// k_wT: transpose per-channel weights so k_main's input-outer loops read
// consecutive addresses (enables s_load_dwordx8/16 batching).
//   W0T[c][i*32+o] = W0[c][o*64+i];  W1T/W2T[c][j*32+o] = W[c][o*32+j]
// ---------------------------------------------------------------------------
__global__ __launch_bounds__(256) void k_wT(const float* __restrict__ W0,
                                            const float* __restrict__ W1,
                                            const float* __restrict__ W2,
                                            float* __restrict__ W0T,
                                            float* __restrict__ W1T,
                                            float* __restrict__ W2T) {
    const int c = blockIdx.x;
    const int tid = threadIdx.x;
#pragma unroll
    for (int rep = 0; rep < 8; ++rep) {
        int idx = tid + rep * 256;              // idx = i*32+o
        int i = idx >> 5, o = idx & 31;
        W0T[c * 2048 + idx] = W0[c * 2048 + o * 64 + i];
    }
#pragma unroll
    for (int rep = 0; rep < 4; ++rep) {
        int idx = tid + rep * 256;              // idx = j*32+o
        int j = idx >> 5, o = idx & 31;
        W1T[c * 1024 + idx] = W1[c * 1024 + o * 32 + j];
        W2T[c * 1024 + idx] = W2[c * 1024 + o * 32 + j];
    }
}

// ---------------------------------------------------------------------------
// k_zadj: per s, build z_lt (strict lower-tri), z_p, then z_p^T @ z_lt @ z_p
// ---------------------------------------------------------------------------
__global__ __launch_bounds__(256) void k_zadj(const float* __restrict__ z,
                                              float* __restrict__ zadj) {
    __shared__ float zp[64 * 64];
    __shared__ float zlt[64 * 64];
    __shared__ float T[64 * 64];
    const int s = blockIdx.x;
    const int tid = threadIdx.x;
    const float* zs = z + (size_t)s * ZROW;

#pragma unroll
    for (int rep = 0; rep < 16; ++rep) {
        int idx = tid + rep * 256;
        zp[idx] = zs[LTW + idx];
        zlt[idx] = 0.0f;
    }
    __syncthreads();
    for (int k = tid; k < LTW; k += 256) {
        float kf = (float)k;
        int r = (int)((1.0f + sqrtf(1.0f + 8.0f * kf)) * 0.5f);
        while (r * (r - 1) / 2 > k) --r;
        while ((r + 1) * r / 2 <= k) ++r;
        int t = k - r * (r - 1) / 2;
        zlt[r * 64 + t] = zs[k];
    }
    __syncthreads();
#pragma unroll
    for (int rep = 0; rep < 16; ++rep) {
        int idx = tid + rep * 256;
        int r = idx >> 6, j = idx & 63;
        float acc = 0.0f;
        for (int t = 0; t < 64; ++t)
            acc = fmaf(zlt[r * 64 + t], zp[t * 64 + j], acc);
        T[idx] = acc;
    }
    __syncthreads();
#pragma unroll
    for (int rep = 0; rep < 16; ++rep) {
        int idx = tid + rep * 256;
        int i = idx >> 6, j = idx & 63;
        float acc = 0.0f;
        for (int r = 0; r < 64; ++r)
            acc = fmaf(zp[r * 64 + i], T[r * 64 + j], acc);
        zadj[(size_t)s * 4096 + idx] = acc;
    }
}

// ---------------------------------------------------------------------------
// k_main: fused 4-layer per-channel MLP, input-outer form.
// Block = (c, s); lane = batch. Max live VGPRs ~75 (h1[32]+h2[32]+temps):
// the Round-1 h[64] spill (218+244 MB scratch traffic) is structurally gone.
// Weights/zadj/bias addresses are wave-uniform -> s_load, FMAs take the
// weight as the SGPR operand.
// ---------------------------------------------------------------------------
template <bool WT>
__global__ __launch_bounds__(256, 3) void k_main(
    const float* __restrict__ xsrc, int xi_s, int xb_s,
    const float* __restrict__ zadj,
    const float* __restrict__ W0, const float* __restrict__ B0,
    const float* __restrict__ W1, const float* __restrict__ B1,
    const float* __restrict__ W2, const float* __restrict__ B2,
    const float* __restrict__ W3, const float* __restrict__ B3,
    float* __restrict__ outp, int o_sS, int o_cS, int o_bS) {
    const int c = blockIdx.x;
    const int s = blockIdx.y;
    const int lane = threadIdx.x & 63;
    const int wave = threadIdx.x >> 6;

    const float* w0c = W0 + c * 2048;
    const float* w1c = W1 + c * 1024;
    const float* w2c = W2 + c * 1024;
    const float* w3c = W3 + c * 32;
    const float* b0c = B0 + c * 32;
    const float* b1c = B1 + c * 32;
    const float* b2c = B2 + c * 32;
    const float b3v = B3[c];
    const float* zc = zadj + s * 4096 + c;   // element i at zc[i*64]

#pragma unroll 1   // keep each bc body within I$
    for (int bc = 0; bc < 2; ++bc) {
        const int b = wave * 128 + bc * 64 + lane;

        float h1[32], h2[32];
        // layer 0 (input-outer): h1[o] = b0[o] + sum_i W0[o,i] * (zadj[s,i,c]*x[b,i])
#pragma unroll
        for (int o = 0; o < 32; ++o) h1[o] = b0c[o];
#pragma unroll 8
        for (int i = 0; i < 64; ++i) {
            float hi = zc[i * 64] * xsrc[i * xi_s + b * xb_s];
#pragma unroll
            for (int o = 0; o < 32; ++o)
                h1[o] = fmaf(WT ? w0c[i * 32 + o] : w0c[o * 64 + i], hi, h1[o]);
        }
        // relu, then layer 1 (input-outer)
#pragma unroll
        for (int o = 0; o < 32; ++o) {
            h1[o] = fmaxf(h1[o], 0.0f);
            h2[o] = b1c[o];
        }
#pragma unroll 8
        for (int j = 0; j < 32; ++j) {
            float v = h1[j];
#pragma unroll
            for (int o = 0; o < 32; ++o)
                h2[o] = fmaf(WT ? w1c[j * 32 + o] : w1c[o * 32 + j], v, h2[o]);
        }
        // relu, then layer 2 (input-outer), back into h1
#pragma unroll
        for (int o = 0; o < 32; ++o) {
            h2[o] = fmaxf(h2[o], 0.0f);
            h1[o] = b2c[o];
        }
#pragma unroll 8
        for (int j = 0; j < 32; ++j) {
            float v = h2[j];
#pragma unroll
            for (int o = 0; o < 32; ++o)
                h1[o] = fmaf(WT ? w2c[j * 32 + o] : w2c[o * 32 + j], v, h1[o]);
        }
        // relu + layer 3 (32 -> 1)
        float a = b3v;
#pragma unroll
        for (int j = 0; j < 32; ++j) a = fmaf(w3c[j], fmaxf(h1[j], 0.0f), a);
        outp[s * o_sS + c * o_cS + b * o_bS] = a;
    }
}

// ---------------------------------------------------------------------------
// k_outT: transpose outT (s,c,b) -> out (b,s,c)
// ---------------------------------------------------------------------------
__global__ __launch_bounds__(256) void k_outT(const float* __restrict__ outT,
                                              float* __restrict__ out) {
    __shared__ float tile[64][65];
    const int bt = blockIdx.x;   // 8 b-tiles
    const int s = blockIdx.y;    // 64
    const int tid = threadIdx.x;
    const int r0 = tid >> 6, q = tid & 63;
#pragma unroll
    for (int rep = 0; rep < 16; ++rep) {
        int crow = rep * 4 + r0;
        tile[crow][q] = outT[(s * 64 + crow) * 512 + bt * 64 + q];
    }
    __syncthreads();
#pragma unroll
    for (int rep = 0; rep < 16; ++rep) {
        int brow = rep * 4 + r0;
        out[(bt * 64 + brow) * 4096 + s * 64 + q] = tile[q][brow];
    }
}

extern "C" void kernel_launch(void* const* d_in, const int* in_sizes, int n_in,
                              void* d_out, int out_size, void* d_ws, size_t ws_size,
                              hipStream_t stream) {
    const float* x  = (const float*)d_in[0];
    const float* z  = (const float*)d_in[1];
    const float* W0 = (const float*)d_in[2];
    const float* B0 = (const float*)d_in[3];
    const float* W1 = (const float*)d_in[4];
    const float* B1 = (const float*)d_in[5];
    const float* W2 = (const float*)d_in[6];
    const float* B2 = (const float*)d_in[7];
    const float* W3 = (const float*)d_in[8];
    const float* B3 = (const float*)d_in[9];

    float* out  = (float*)d_out;
    float* zadj = out + ZADJ_OFF;

    // workspace layout: xT | outT | W0T | W1T | W2T
    const size_t XT_B  = 64 * 512 * sizeof(float);            // 131072
    const size_t OT_B  = (size_t)S * D * BSZ * sizeof(float); // 8388608
    const size_t W0T_B = 64 * 2048 * sizeof(float);           // 524288
    const size_t W1T_B = 64 * 1024 * sizeof(float);           // 262144
    const size_t W2T_B = 64 * 1024 * sizeof(float);           // 262144
    const bool has_xT = ws_size >= XT_B;
    const bool has_oT = ws_size >= XT_B + OT_B;
    const bool has_wT = ws_size >= XT_B + OT_B + W0T_B + W1T_B + W2T_B;

    char* wsb = (char*)d_ws;
    float* xT   = (float*)wsb;
    float* outT = (float*)(wsb + XT_B);
    float* W0T  = (float*)(wsb + XT_B + OT_B);
    float* W1T  = (float*)(wsb + XT_B + OT_B + W0T_B);
    float* W2T  = (float*)(wsb + XT_B + OT_B + W0T_B + W1T_B);

    hipLaunchKernelGGL(k_zadj, dim3(S), dim3(256), 0, stream, z, zadj);
    if (has_xT)
        hipLaunchKernelGGL(k_xT, dim3(8), dim3(256), 0, stream, x, xT);
    if (has_wT)
        hipLaunchKernelGGL(k_wT, dim3(64), dim3(256), 0, stream,
                           W0, W1, W2, W0T, W1T, W2T);

    const float* xs = has_xT ? (const float*)xT : x;
    const int xi_s = has_xT ? 512 : 1;
    const int xb_s = has_xT ? 1 : 64;
    float* op = has_oT ? outT : out;
    const int o_sS = has_oT ? (64 * 512) : 64;
    const int o_cS = has_oT ? 512 : 1;
    const int o_bS = has_oT ? 1 : 4096;

    if (has_wT)
        hipLaunchKernelGGL((k_main<true>), dim3(D, S), dim3(256), 0, stream,
                           xs, xi_s, xb_s, zadj,
                           W0T, B0, W1T, B1, W2T, B2, W3, B3,
                           op, o_sS, o_cS, o_bS);
    else
        hipLaunchKernelGGL((k_main<false>), dim3(D, S), dim3(256), 0, stream,
                           xs, xi_s, xb_s, zadj,
                           W0, B0, W1, B1, W2, B2, W3, B3,
                           op, o_sS, o_cS, o_bS);

    if (has_oT)
        hipLaunchKernelGGL(k_outT, dim3(8, S), dim3(256), 0, stream, outT, out);
}

// Round 3
// 158.158 us; speedup vs baseline: 6.6741x; 1.9685x over previous
//
#include <hip/hip_runtime.h>
#include <math.h>

#define D 64
#define S 64
#define BSZ 512
#define LTW 2016
#define ZROW 6112
#define OUT0_SIZE (BSZ * S * D)   // 2097152 floats
#define ZADJ_OFF  OUT0_SIZE

typedef float  f32x4  __attribute__((ext_vector_type(4)));
typedef short  bf16x8 __attribute__((ext_vector_type(8)));

// ---------------------------------------------------------------------------
// bf16 hi/lo split helpers (truncation split: a = hi + lo exactly at fp32;
// hi,lo each representable in bf16 -> product chain rel err ~2^-16)
// ---------------------------------------------------------------------------
__device__ __forceinline__ float trunc_bf(float a) {
    return __uint_as_float(__float_as_uint(a) & 0xffff0000u);
}
__device__ __forceinline__ unsigned pack_hi(float a0, float a1) {
    unsigned b0 = __float_as_uint(a0) & 0xffff0000u;
    unsigned b1 = __float_as_uint(a1) & 0xffff0000u;
    return (b0 >> 16) | b1;
}
__device__ __forceinline__ void split8(const float* e, bf16x8& hi, bf16x8& lo) {
    float r[8];
#pragma unroll
    for (int j = 0; j < 8; ++j) r[j] = e[j] - trunc_bf(e[j]);
    uint4 h, l;
    h.x = pack_hi(e[0], e[1]); h.y = pack_hi(e[2], e[3]);
    h.z = pack_hi(e[4], e[5]); h.w = pack_hi(e[6], e[7]);
    l.x = pack_hi(r[0], r[1]); l.y = pack_hi(r[2], r[3]);
    l.z = pack_hi(r[4], r[5]); l.w = pack_hi(r[6], r[7]);
    hi = __builtin_bit_cast(bf16x8, h);
    lo = __builtin_bit_cast(bf16x8, l);
}

// ---------------------------------------------------------------------------
// k_zadj: block (s, jt): z_p^T @ z_lt @ z_p, 16 j-columns per block (256 blocks)
// ---------------------------------------------------------------------------
__global__ __launch_bounds__(256) void k_zadj(const float* __restrict__ z,
                                              float* __restrict__ zadj) {
    __shared__ float zp[4096];
    __shared__ float zlt[4096];
    __shared__ float T[1024];
    const int s = blockIdx.x, jt = blockIdx.y;
    const int tid = threadIdx.x;
    const float* zs = z + (size_t)s * ZROW;

#pragma unroll
    for (int rep = 0; rep < 16; ++rep) {
        int idx = tid + rep * 256;
        zp[idx] = zs[LTW + idx];
        zlt[idx] = 0.0f;
    }
    __syncthreads();
    for (int k = tid; k < LTW; k += 256) {
        float kf = (float)k;
        int r = (int)((1.0f + sqrtf(1.0f + 8.0f * kf)) * 0.5f);
        while (r * (r - 1) / 2 > k) --r;
        while ((r + 1) * r / 2 <= k) ++r;
        int t = k - r * (r - 1) / 2;
        zlt[r * 64 + t] = zs[k];
    }
    __syncthreads();
    // T[r][jj] = sum_t zlt[r][t] * zp[t][jt*16+jj]
#pragma unroll
    for (int rep = 0; rep < 4; ++rep) {
        int e = tid + rep * 256;
        int r = e >> 4, jj = e & 15;
        float acc = 0.0f;
        for (int t = 0; t < 64; ++t)
            acc = fmaf(zlt[r * 64 + t], zp[t * 64 + jt * 16 + jj], acc);
        T[e] = acc;
    }
    __syncthreads();
    // zadj[i][j] = sum_r zp[r][i] * T[r][jj]
#pragma unroll
    for (int rep = 0; rep < 4; ++rep) {
        int e = tid + rep * 256;
        int i = e >> 4, jj = e & 15;
        float acc = 0.0f;
        for (int r = 0; r < 64; ++r)
            acc = fmaf(zp[r * 64 + i], T[r * 16 + jj], acc);
        zadj[(size_t)s * 4096 + i * 64 + jt * 16 + jj] = acc;
    }
}

// ---------------------------------------------------------------------------
// k_prep: build MFMA fragment buffers.
//  - w0f: W0 in A-frag order, fp32 (scaled by z at runtime in k_main)
//  - w1f/w2f: W1/W2 in A-frag order, pre-split bf16 hi/lo
//  - xf: x in B-frag order, pre-split bf16 hi/lo
// Frag conventions (16x16x32 bf16):
//   A[m=lane&15][k=quad*8+j], B[k=quad*8+j][n=lane&15], C/D col=lane&15,row=quad*4+reg
// ---------------------------------------------------------------------------
__global__ __launch_bounds__(256) void k_prep(const float* __restrict__ x,
                                              const float* __restrict__ W0,
                                              const float* __restrict__ W1,
                                              const float* __restrict__ W2,
                                              float* __restrict__ w0f,
                                              uint4* __restrict__ w1f,
                                              uint4* __restrict__ w2f,
                                              uint4* __restrict__ xf) {
    const int c = blockIdx.x, tid = threadIdx.x;
    // --- W0 fp32 reorder: slot = (Mt*2+ks)*64+lane
    {
        int Mt = tid >> 7, ks = (tid >> 6) & 1, ln = tid & 63;
        int o = Mt * 16 + (ln & 15), kb = ks * 32 + ((ln >> 4)) * 8;
        const f32x4* src = (const f32x4*)(W0 + c * 2048 + o * 64 + kb);
        f32x4* dst = (f32x4*)(w0f + c * 2048 + tid * 8);
        dst[0] = src[0];
        dst[1] = src[1];
    }
    // --- W1/W2 split frags: 128 slots each, slot = Mt*64+lane
    {
        const float* W = (tid < 128) ? W1 : W2;
        uint4* dstb = (tid < 128) ? w1f : w2f;
        int t2 = tid & 127;
        int Mt = t2 >> 6, ln = t2 & 63;
        int o = Mt * 16 + (ln & 15), kb = (ln >> 4) * 8;
        const float* src = W + c * 1024 + o * 32 + kb;
        float e[8];
#pragma unroll
        for (int j = 0; j < 8; ++j) e[j] = src[j];
        bf16x8 hi, lo;
        split8(e, hi, lo);
        dstb[c * 256 + t2 * 2]     = __builtin_bit_cast(uint4, hi);
        dstb[c * 256 + t2 * 2 + 1] = __builtin_bit_cast(uint4, lo);
    }
    // --- x B-frags: 4096 slots total; block c handles slots [c*64, c*64+64)
    if (tid < 64) {
        int slot = c * 64 + tid;
        int ln = slot & 63, ks = (slot >> 6) & 1, bt = slot >> 7;
        int b = bt * 16 + (ln & 15), kb = ks * 32 + (ln >> 4) * 8;
        const float* src = x + b * 64 + kb;
        float e[8];
#pragma unroll
        for (int j = 0; j < 8; ++j) e[j] = src[j];
        bf16x8 hi, lo;
        split8(e, hi, lo);
        xf[slot * 2]     = __builtin_bit_cast(uint4, hi);
        xf[slot * 2 + 1] = __builtin_bit_cast(uint4, lo);
    }
}

// ---------------------------------------------------------------------------
// C/D -> next-layer B-frag via per-wave LDS round trip (no block barrier:
// DS ops from one wave are in-order; lgkmcnt(0) drains writes before reads).
// scr layout per wave: [b=l15][o(32) + pad4] = 36 floats/row.
// ---------------------------------------------------------------------------
__device__ __forceinline__ void transition(float* scrw, int l15, int quad,
                                           f32x4 accin0, f32x4 accin1,
                                           const float* bv,
                                           bf16x8& bh, bf16x8& bl) {
    f32x4* wp = (f32x4*)(scrw + l15 * 36 + quad * 4);
    wp[0] = accin0;   // o = 0  + quad*4 + r
    wp[4] = accin1;   // o = 16 + quad*4 + r
    asm volatile("s_waitcnt lgkmcnt(0)" ::: "memory");
    const float* rp = scrw + l15 * 36 + quad * 8;
    float e[8];
#pragma unroll
    for (int j = 0; j < 8; ++j) e[j] = fmaxf(rp[j] + bv[j], 0.0f);
    split8(e, bh, bl);
}

#define MFMA3(accv, ah, al, bhv, blv)                                          \
    accv = __builtin_amdgcn_mfma_f32_16x16x32_bf16(ah, bhv, accv, 0, 0, 0);    \
    accv = __builtin_amdgcn_mfma_f32_16x16x32_bf16(al, bhv, accv, 0, 0, 0);    \
    accv = __builtin_amdgcn_mfma_f32_16x16x32_bf16(ah, blv, accv, 0, 0, 0);

// ---------------------------------------------------------------------------
// k_main_mfma: transposed-domain fused MLP. Block=(bh,c,s); wave handles 64 b.
// Layer l: D = W_l^eff (M=o_out, K=o_in) x activations^T (K, N=b).
// ---------------------------------------------------------------------------
__global__ __launch_bounds__(256, 3) void k_main_mfma(
    const uint4* __restrict__ xf, const float* __restrict__ w0f,
    const uint4* __restrict__ w1f, const uint4* __restrict__ w2f,
    const float* __restrict__ zadj,
    const float* __restrict__ B0, const float* __restrict__ B1,
    const float* __restrict__ B2, const float* __restrict__ W3,
    const float* __restrict__ B3, float* __restrict__ outT) {
    __shared__ float scr[4 * 576];
    const int bh = blockIdx.x, c = blockIdx.y, s = blockIdx.z;
    const int tid = threadIdx.x;
    const int wave = tid >> 6, lane = tid & 63;
    const int quad = lane >> 4, l15 = lane & 15;
    float* scrw = scr + wave * 576;
    const int btbase = bh * 16 + wave * 4;

    const f32x4 zero4 = {0.0f, 0.0f, 0.0f, 0.0f};
    f32x4 acc0[2][4];
#pragma unroll
    for (int Mt = 0; Mt < 2; ++Mt)
#pragma unroll
        for (int Nt = 0; Nt < 4; ++Nt) acc0[Mt][Nt] = zero4;

    // ---------------- layer 0: W0eff (32x64) x x^T (64x64b) ----------------
#pragma unroll
    for (int ks = 0; ks < 2; ++ks) {
        // z values for k = ks*32 + quad*8 + j  (zadj[s][k][c], stride 64)
        const float* zp = zadj + (size_t)s * 4096 + (ks * 32 + quad * 8) * 64 + c;
        float zv[8];
#pragma unroll
        for (int j = 0; j < 8; ++j) zv[j] = zp[j * 64];
        bf16x8 ahi[2], alo[2];
#pragma unroll
        for (int Mt = 0; Mt < 2; ++Mt) {
            const float* wp = w0f + c * 2048 + ((Mt * 2 + ks) * 64 + lane) * 8;
            float e[8];
#pragma unroll
            for (int j = 0; j < 8; ++j) e[j] = wp[j] * zv[j];
            split8(e, ahi[Mt], alo[Mt]);
        }
#pragma unroll
        for (int Nt = 0; Nt < 4; ++Nt) {
            const uint4* xp = xf + ((size_t)(btbase + Nt) * 2 + ks) * 128 + lane * 2;
            bf16x8 xh = __builtin_bit_cast(bf16x8, xp[0]);
            bf16x8 xl = __builtin_bit_cast(bf16x8, xp[1]);
#pragma unroll
            for (int Mt = 0; Mt < 2; ++Mt) {
                MFMA3(acc0[Mt][Nt], ahi[Mt], alo[Mt], xh, xl);
            }
        }
    }

    // hoisted A-frags + biases for layers 1/2
    bf16x8 a1h[2], a1l[2], a2h[2], a2l[2];
#pragma unroll
    for (int Mt = 0; Mt < 2; ++Mt) {
        const uint4* p1 = w1f + c * 256 + (Mt * 64 + lane) * 2;
        const uint4* p2 = w2f + c * 256 + (Mt * 64 + lane) * 2;
        a1h[Mt] = __builtin_bit_cast(bf16x8, p1[0]);
        a1l[Mt] = __builtin_bit_cast(bf16x8, p1[1]);
        a2h[Mt] = __builtin_bit_cast(bf16x8, p2[0]);
        a2l[Mt] = __builtin_bit_cast(bf16x8, p2[1]);
    }
    float bv0[8], bv1[8];
    {
        const float* b0p = B0 + c * 32 + quad * 8;
        const float* b1p = B1 + c * 32 + quad * 8;
#pragma unroll
        for (int j = 0; j < 8; ++j) { bv0[j] = b0p[j]; bv1[j] = b1p[j]; }
    }

    // ---------------- layer 1 ----------------
    f32x4 acc1[2][4];
#pragma unroll
    for (int Mt = 0; Mt < 2; ++Mt)
#pragma unroll
        for (int Nt = 0; Nt < 4; ++Nt) acc1[Mt][Nt] = zero4;
#pragma unroll
    for (int Nt = 0; Nt < 4; ++Nt) {
        bf16x8 bhv, blv;
        transition(scrw, l15, quad, acc0[0][Nt], acc0[1][Nt], bv0, bhv, blv);
#pragma unroll
        for (int Mt = 0; Mt < 2; ++Mt) { MFMA3(acc1[Mt][Nt], a1h[Mt], a1l[Mt], bhv, blv); }
    }

    // ---------------- layer 2 ----------------
    f32x4 acc2[2][4];
#pragma unroll
    for (int Mt = 0; Mt < 2; ++Mt)
#pragma unroll
        for (int Nt = 0; Nt < 4; ++Nt) acc2[Mt][Nt] = zero4;
#pragma unroll
    for (int Nt = 0; Nt < 4; ++Nt) {
        bf16x8 bhv, blv;
        transition(scrw, l15, quad, acc1[0][Nt], acc1[1][Nt], bv1, bhv, blv);
#pragma unroll
        for (int Mt = 0; Mt < 2; ++Mt) { MFMA3(acc2[Mt][Nt], a2h[Mt], a2l[Mt], bhv, blv); }
    }

    // ---------------- layer 3: relu(acc2 + b2) . w3 + b3, VALU + shfl ------
    float w3v[8], b2v[8];
#pragma unroll
    for (int t = 0; t < 2; ++t) {
        const float* wp3 = W3 + c * 32 + t * 16 + quad * 4;
        const float* bp2 = B2 + c * 32 + t * 16 + quad * 4;
#pragma unroll
        for (int r = 0; r < 4; ++r) { w3v[t * 4 + r] = wp3[r]; b2v[t * 4 + r] = bp2[r]; }
    }
    const float b3v = B3[c];
    float red[4];
#pragma unroll
    for (int Nt = 0; Nt < 4; ++Nt) {
        float p = 0.0f;
#pragma unroll
        for (int t = 0; t < 2; ++t)
#pragma unroll
            for (int r = 0; r < 4; ++r) {
                float v = fmaxf(acc2[t][Nt][r] + b2v[t * 4 + r], 0.0f);
                p = fmaf(w3v[t * 4 + r], v, p);
            }
        p += __shfl_xor(p, 16, 64);
        p += __shfl_xor(p, 32, 64);
        red[Nt] = p;
    }
    float outv = (quad & 2) ? ((quad & 1) ? red[3] : red[2])
                            : ((quad & 1) ? red[1] : red[0]);
    outv += b3v;
    // lane (quad,l15) stores b for Nt=quad -> fully coalesced 256B per wave
    outT[((size_t)s * 64 + c) * 512 + bh * 256 + wave * 64 + lane] = outv;
}

// ---------------------------------------------------------------------------
// Fallback VALU kernel (round-2 proven path), raw layouts only.
// ---------------------------------------------------------------------------
__global__ __launch_bounds__(256, 3) void k_main_valu(
    const float* __restrict__ xsrc, const float* __restrict__ zadj,
    const float* __restrict__ W0, const float* __restrict__ B0,
    const float* __restrict__ W1, const float* __restrict__ B1,
    const float* __restrict__ W2, const float* __restrict__ B2,
    const float* __restrict__ W3, const float* __restrict__ B3,
    float* __restrict__ outp, int o_sS, int o_cS, int o_bS) {
    const int c = blockIdx.x;
    const int s = blockIdx.y;
    const int lane = threadIdx.x & 63;
    const int wave = threadIdx.x >> 6;

    const float* w0c = W0 + c * 2048;
    const float* w1c = W1 + c * 1024;
    const float* w2c = W2 + c * 1024;
    const float* w3c = W3 + c * 32;
    const float* b0c = B0 + c * 32;
    const float* b1c = B1 + c * 32;
    const float* b2c = B2 + c * 32;
    const float b3v = B3[c];
    const float* zc = zadj + s * 4096 + c;

#pragma unroll 1
    for (int bc = 0; bc < 2; ++bc) {
        const int b = wave * 128 + bc * 64 + lane;
        float h1[32], h2[32];
#pragma unroll
        for (int o = 0; o < 32; ++o) h1[o] = b0c[o];
#pragma unroll 8
        for (int i = 0; i < 64; ++i) {
            float hi = zc[i * 64] * xsrc[b * 64 + i];
#pragma unroll
            for (int o = 0; o < 32; ++o) h1[o] = fmaf(w0c[o * 64 + i], hi, h1[o]);
        }
#pragma unroll
        for (int o = 0; o < 32; ++o) { h1[o] = fmaxf(h1[o], 0.0f); h2[o] = b1c[o]; }
#pragma unroll 8
        for (int j = 0; j < 32; ++j) {
            float v = h1[j];
#pragma unroll
            for (int o = 0; o < 32; ++o) h2[o] = fmaf(w1c[o * 32 + j], v, h2[o]);
        }
#pragma unroll
        for (int o = 0; o < 32; ++o) { h2[o] = fmaxf(h2[o], 0.0f); h1[o] = b2c[o]; }
#pragma unroll 8
        for (int j = 0; j < 32; ++j) {
            float v = h2[j];
#pragma unroll
            for (int o = 0; o < 32; ++o) h1[o] = fmaf(w2c[o * 32 + j], v, h1[o]);
        }
        float a = b3v;
#pragma unroll
        for (int j = 0; j < 32; ++j) a = fmaf(w3c[j], fmaxf(h1[j], 0.0f), a);
        outp[s * o_sS + c * o_cS + b * o_bS] = a;
    }
}

// ---------------------------------------------------------------------------
// k_outT: transpose outT (s,c,b) -> out (b,s,c)
// ---------------------------------------------------------------------------
__global__ __launch_bounds__(256) void k_outT(const float* __restrict__ outT,
                                              float* __restrict__ out) {
    __shared__ float tile[64][65];
    const int bt = blockIdx.x;
    const int s = blockIdx.y;
    const int tid = threadIdx.x;
    const int r0 = tid >> 6, q = tid & 63;
#pragma unroll
    for (int rep = 0; rep < 16; ++rep) {
        int crow = rep * 4 + r0;
        tile[crow][q] = outT[(s * 64 + crow) * 512 + bt * 64 + q];
    }
    __syncthreads();
#pragma unroll
    for (int rep = 0; rep < 16; ++rep) {
        int brow = rep * 4 + r0;
        out[(bt * 64 + brow) * 4096 + s * 64 + q] = tile[q][brow];
    }
}

extern "C" void kernel_launch(void* const* d_in, const int* in_sizes, int n_in,
                              void* d_out, int out_size, void* d_ws, size_t ws_size,
                              hipStream_t stream) {
    const float* x  = (const float*)d_in[0];
    const float* z  = (const float*)d_in[1];
    const float* W0 = (const float*)d_in[2];
    const float* B0 = (const float*)d_in[3];
    const float* W1 = (const float*)d_in[4];
    const float* B1 = (const float*)d_in[5];
    const float* W2 = (const float*)d_in[6];
    const float* B2 = (const float*)d_in[7];
    const float* W3 = (const float*)d_in[8];
    const float* B3 = (const float*)d_in[9];

    float* out  = (float*)d_out;
    float* zadj = out + ZADJ_OFF;

    // workspace: outT | xf | w0f | w1f | w2f  (total 9,568,256 B)
    const size_t OT_B  = (size_t)S * D * BSZ * sizeof(float); // 8388608
    const size_t XF_B  = 4096 * 32;                           // 131072
    const size_t W0F_B = 64 * 2048 * sizeof(float);           // 524288
    const size_t W1F_B = 64 * 128 * 32;                       // 262144
    const size_t W2F_B = W1F_B;
    const bool has_oT   = ws_size >= OT_B;
    const bool has_frag = ws_size >= OT_B + XF_B + W0F_B + W1F_B + W2F_B;

    char* wsb = (char*)d_ws;
    float* outT = (float*)wsb;
    uint4* xf   = (uint4*)(wsb + OT_B);
    float* w0f  = (float*)(wsb + OT_B + XF_B);
    uint4* w1f  = (uint4*)(wsb + OT_B + XF_B + W0F_B);
    uint4* w2f  = (uint4*)(wsb + OT_B + XF_B + W0F_B + W1F_B);

    hipLaunchKernelGGL(k_zadj, dim3(S, 4), dim3(256), 0, stream, z, zadj);

    if (has_frag) {
        hipLaunchKernelGGL(k_prep, dim3(64), dim3(256), 0, stream,
                           x, W0, W1, W2, w0f, w1f, w2f, xf);
        hipLaunchKernelGGL(k_main_mfma, dim3(2, 64, 64), dim3(256), 0, stream,
                           xf, w0f, w1f, w2f, zadj,
                           B0, B1, B2, W3, B3, outT);
        hipLaunchKernelGGL(k_outT, dim3(8, S), dim3(256), 0, stream, outT, out);
    } else {
        float* op = has_oT ? outT : out;
        const int o_sS = has_oT ? (64 * 512) : 64;
        const int o_cS = has_oT ? 512 : 1;
        const int o_bS = has_oT ? 1 : 4096;
        hipLaunchKernelGGL(k_main_valu, dim3(D, S), dim3(256), 0, stream,
                           x, zadj, W0, B0, W1, B1, W2, B2, W3, B3,
                           op, o_sS, o_cS, o_bS);
        if (has_oT)
            hipLaunchKernelGGL(k_outT, dim3(8, S), dim3(256), 0, stream, outT, out);
    }
}

// Round 5
// 145.927 us; speedup vs baseline: 7.2335x; 1.0838x over previous
//
#include <hip/hip_runtime.h>
#include <math.h>

#define D 64
#define S 64
#define BSZ 512
#define LTW 2016
#define ZROW 6112
#define OUT0_SIZE (BSZ * S * D)   // 2097152 floats
#define ZADJ_OFF  OUT0_SIZE

typedef float    f32x4 __attribute__((ext_vector_type(4)));
typedef _Float16 f16x8 __attribute__((ext_vector_type(8)));
typedef _Float16 f16x4 __attribute__((ext_vector_type(4)));
typedef _Float16 f16x2 __attribute__((ext_vector_type(2)));

union V8 { f16x8 v; f16x2 h2[4]; uint4 u; };
union V4 { f16x4 v; f16x2 h2[2]; uint2 u; };

__device__ __forceinline__ f16x2 pkrtz(float a, float b) {
    return __builtin_bit_cast(f16x2, __builtin_amdgcn_cvt_pkrtz(a, b));
}

__device__ __forceinline__ f32x4 mfma_x16(f16x4 a, f16x4 b, f32x4 c) {
    return __builtin_amdgcn_mfma_f32_16x16x16f16(a, b, c, 0, 0, 0);
}

// ---------------------------------------------------------------------------
// k_zadjprep: blocks 0..255 -> z_adj (s = blk>>2, jt = blk&3)
//             blocks 256..319 -> fragment prep for channel c = blk-256
// ---------------------------------------------------------------------------
__global__ __launch_bounds__(256) void k_zadjprep(
    const float* __restrict__ z, float* __restrict__ zadj,
    const float* __restrict__ x,
    const float* __restrict__ W0, const float* __restrict__ W1,
    const float* __restrict__ W2,
    uint4* __restrict__ w0f, uint2* __restrict__ w1f,
    uint2* __restrict__ w2f, uint4* __restrict__ xf) {
    __shared__ float zp[4096];
    __shared__ float zlt[4096];
    __shared__ float T[1024];
    const int blk = blockIdx.x;
    const int tid = threadIdx.x;

    if (blk < 256) {
        const int s = blk >> 2, jt = blk & 3;
        const float* zs = z + (size_t)s * ZROW;
#pragma unroll
        for (int rep = 0; rep < 16; ++rep) {
            int idx = tid + rep * 256;
            zp[idx] = zs[LTW + idx];
            zlt[idx] = 0.0f;
        }
        __syncthreads();
        for (int k = tid; k < LTW; k += 256) {
            float kf = (float)k;
            int r = (int)((1.0f + sqrtf(1.0f + 8.0f * kf)) * 0.5f);
            while (r * (r - 1) / 2 > k) --r;
            while ((r + 1) * r / 2 <= k) ++r;
            int t = k - r * (r - 1) / 2;
            zlt[r * 64 + t] = zs[k];
        }
        __syncthreads();
#pragma unroll
        for (int rep = 0; rep < 4; ++rep) {
            int e = tid + rep * 256;
            int r = e >> 4, jj = e & 15;
            float acc = 0.0f;
            for (int t = 0; t < 64; ++t)
                acc = fmaf(zlt[r * 64 + t], zp[t * 64 + jt * 16 + jj], acc);
            T[e] = acc;
        }
        __syncthreads();
#pragma unroll
        for (int rep = 0; rep < 4; ++rep) {
            int e = tid + rep * 256;
            int i = e >> 4, jj = e & 15;
            float acc = 0.0f;
            for (int r = 0; r < 64; ++r)
                acc = fmaf(zp[r * 64 + i], T[r * 16 + jj], acc);
            zadj[(size_t)s * 4096 + i * 64 + jt * 16 + jj] = acc;
        }
    } else {
        const int c = blk - 256;
        const int sl = tid >> 6, ln = tid & 63;
        const int q = ln >> 4, l15 = ln & 15;
        // --- W0 A-frags (16x16x32 f16): A[m=Mt*16+l15][k=ks*32+q*8+j]
        {
            int Mt = sl >> 1, ks = sl & 1;
            const float* src = W0 + c * 2048 + (Mt * 16 + l15) * 64 + ks * 32 + q * 8;
            V8 hi, lo;
#pragma unroll
            for (int j = 0; j < 8; ++j) {
                float e = src[j];
                _Float16 h = (_Float16)e;          // RNE
                hi.v[j] = h;
                lo.v[j] = (_Float16)(e - (float)h);
            }
            uint4* dst = w0f + ((size_t)(c * 4 + sl) * 64 + ln) * 2;
            dst[0] = hi.u;
            dst[1] = lo.u;
        }
        // --- W1/W2 A-frags (16x16x16 f16): A[m=Mt*16+l15][k=kc*16+q*4+j]
        {
            int Mt = sl >> 1, kc = sl & 1;
#pragma unroll
            for (int w = 0; w < 2; ++w) {
                const float* Wsrc = w ? W2 : W1;
                uint2* dstb = w ? w2f : w1f;
                const float* src = Wsrc + c * 1024 + (Mt * 16 + l15) * 32 + kc * 16 + q * 4;
                V4 hi, lo;
#pragma unroll
                for (int j = 0; j < 4; ++j) {
                    float e = src[j];
                    _Float16 h = (_Float16)e;
                    hi.v[j] = h;
                    lo.v[j] = (_Float16)(e - (float)h);
                }
                dstb[((size_t)(c * 4 + sl) * 2 + 0) * 64 + ln] = hi.u;
                dstb[((size_t)(c * 4 + sl) * 2 + 1) * 64 + ln] = lo.u;
            }
        }
        // --- x B-frags (16x16x32 f16): B[k=ks*32+q*8+j][n=bt*16+l15], f16 RNE
        if (tid < 64) {
            int f = c * 64 + tid;
            int fln = f & 63, ks = (f >> 6) & 1, bt = f >> 7;
            int n = bt * 16 + (fln & 15), i0 = ks * 32 + (fln >> 4) * 8;
            const float* src = x + n * 64 + i0;
            V8 hv;
#pragma unroll
            for (int j = 0; j < 8; ++j) hv.v[j] = (_Float16)src[j];
            xf[f] = hv.u;
        }
    }
}

// ---------------------------------------------------------------------------
// k_main_mfma: fused 4-layer per-channel MLP, all-register dataflow.
// Layers 1/2 use 16x16x16 f16 so the C/D->B handoff is in-lane (relu+cvt only).
// 2-term split: weights hi/lo (offline), activations single f16.
// Biases folded into accumulator init. Zero LDS.
// ---------------------------------------------------------------------------
__global__ __launch_bounds__(256, 3) void k_main_mfma(
    const uint4* __restrict__ xf, const uint4* __restrict__ w0f,
    const uint2* __restrict__ w1f, const uint2* __restrict__ w2f,
    const float* __restrict__ zadj,
    const float* __restrict__ B0, const float* __restrict__ B1,
    const float* __restrict__ B2, const float* __restrict__ W3,
    const float* __restrict__ B3, float* __restrict__ outT) {
    const int bh = blockIdx.x;              // b-half (256 b's)
    const int c = blockIdx.y, s = blockIdx.z;
    const int tid = threadIdx.x;
    const int wave = tid >> 6, lane = tid & 63;
    const int quad = lane >> 4;
    const int btbase = bh * 16 + wave * 4;  // 16-wide b-tiles

    // ---- z as f16 pairs for k = ks*32 + quad*8 + j
    f16x2 zvh[2][4];
#pragma unroll
    for (int ks = 0; ks < 2; ++ks) {
        const float* zp = zadj + (size_t)s * 4096 + (ks * 32 + quad * 8) * 64 + c;
        float zv[8];
#pragma unroll
        for (int j = 0; j < 8; ++j) zv[j] = zp[j * 64];
#pragma unroll
        for (int t = 0; t < 4; ++t)
            zvh[ks][t] = pkrtz(zv[2 * t], zv[2 * t + 1]);
    }

    // ---- weight fragments (hi/lo)
    f16x8 a0h[2][2], a0l[2][2];   // [Mt][ks]
#pragma unroll
    for (int Mt = 0; Mt < 2; ++Mt)
#pragma unroll
        for (int ks = 0; ks < 2; ++ks) {
            const uint4* p = w0f + ((size_t)(c * 4 + Mt * 2 + ks) * 64 + lane) * 2;
            V8 h, l; h.u = p[0]; l.u = p[1];
            a0h[Mt][ks] = h.v; a0l[Mt][ks] = l.v;
        }
    f16x4 a1h[2][2], a1l[2][2], a2h[2][2], a2l[2][2];   // [Mt][kc]
#pragma unroll
    for (int Mt = 0; Mt < 2; ++Mt)
#pragma unroll
        for (int kc = 0; kc < 2; ++kc) {
            size_t base = (size_t)(c * 4 + Mt * 2 + kc) * 2;
            V4 t;
            t.u = w1f[(base + 0) * 64 + lane]; a1h[Mt][kc] = t.v;
            t.u = w1f[(base + 1) * 64 + lane]; a1l[Mt][kc] = t.v;
            t.u = w2f[(base + 0) * 64 + lane]; a2h[Mt][kc] = t.v;
            t.u = w2f[(base + 1) * 64 + lane]; a2l[Mt][kc] = t.v;
        }

    // ---- biases / w3 (per-lane rows o = Mt*16 + quad*4 + r)
    f32x4 b0v[2], b1v[2], b2v[2], w3v[2];
#pragma unroll
    for (int Mt = 0; Mt < 2; ++Mt) {
        int off = c * 32 + Mt * 16 + quad * 4;
        b0v[Mt] = *(const f32x4*)(B0 + off);
        b1v[Mt] = *(const f32x4*)(B1 + off);
        b2v[Mt] = *(const f32x4*)(B2 + off);
        w3v[Mt] = *(const f32x4*)(W3 + off);
    }
    const float b3v = B3[c];

    float red[4];
#pragma unroll
    for (int Nt = 0; Nt < 4; ++Nt) {
        // ---------- layer 0 ----------
        f32x4 acc0[2] = {b0v[0], b0v[1]};
#pragma unroll
        for (int ks = 0; ks < 2; ++ks) {
            V8 xv; xv.u = xf[(size_t)((btbase + Nt) * 2 + ks) * 64 + lane];
            V8 bp;
#pragma unroll
            for (int t = 0; t < 4; ++t) bp.h2[t] = zvh[ks][t] * xv.h2[t];
#pragma unroll
            for (int Mt = 0; Mt < 2; ++Mt) {
                acc0[Mt] = __builtin_amdgcn_mfma_f32_16x16x32_f16(a0h[Mt][ks], bp.v, acc0[Mt], 0, 0, 0);
                acc0[Mt] = __builtin_amdgcn_mfma_f32_16x16x32_f16(a0l[Mt][ks], bp.v, acc0[Mt], 0, 0, 0);
            }
        }
        // ---------- transition 0->1 (in-lane: C/D row=quad*4+r == B k=quad*4+r) --
        f16x4 bb[2];
#pragma unroll
        for (int kc = 0; kc < 2; ++kc) {
            V4 t;
            t.h2[0] = pkrtz(fmaxf(acc0[kc][0], 0.0f), fmaxf(acc0[kc][1], 0.0f));
            t.h2[1] = pkrtz(fmaxf(acc0[kc][2], 0.0f), fmaxf(acc0[kc][3], 0.0f));
            bb[kc] = t.v;
        }
        // ---------- layer 1 ----------
        f32x4 acc1[2] = {b1v[0], b1v[1]};
#pragma unroll
        for (int kc = 0; kc < 2; ++kc)
#pragma unroll
            for (int Mt = 0; Mt < 2; ++Mt) {
                acc1[Mt] = mfma_x16(a1h[Mt][kc], bb[kc], acc1[Mt]);
                acc1[Mt] = mfma_x16(a1l[Mt][kc], bb[kc], acc1[Mt]);
            }
        // ---------- transition 1->2 ----------
        f16x4 cc[2];
#pragma unroll
        for (int kc = 0; kc < 2; ++kc) {
            V4 t;
            t.h2[0] = pkrtz(fmaxf(acc1[kc][0], 0.0f), fmaxf(acc1[kc][1], 0.0f));
            t.h2[1] = pkrtz(fmaxf(acc1[kc][2], 0.0f), fmaxf(acc1[kc][3], 0.0f));
            cc[kc] = t.v;
        }
        // ---------- layer 2 ----------
        f32x4 acc2[2] = {b2v[0], b2v[1]};
#pragma unroll
        for (int kc = 0; kc < 2; ++kc)
#pragma unroll
            for (int Mt = 0; Mt < 2; ++Mt) {
                acc2[Mt] = mfma_x16(a2h[Mt][kc], cc[kc], acc2[Mt]);
                acc2[Mt] = mfma_x16(a2l[Mt][kc], cc[kc], acc2[Mt]);
            }
        // ---------- layer 3 partial: relu(acc2) . w3 ----------
        float p = 0.0f;
#pragma unroll
        for (int Mt = 0; Mt < 2; ++Mt)
#pragma unroll
            for (int r = 0; r < 4; ++r)
                p = fmaf(w3v[Mt][r], fmaxf(acc2[Mt][r], 0.0f), p);
        p += __shfl_xor(p, 16, 64);
        p += __shfl_xor(p, 32, 64);
        red[Nt] = p;
    }
    float outv = (quad & 2) ? ((quad & 1) ? red[3] : red[2])
                            : ((quad & 1) ? red[1] : red[0]);
    outv += b3v;
    outT[((size_t)s * 64 + c) * 512 + bh * 256 + tid] = outv;
}

// ---------------------------------------------------------------------------
// Fallback VALU kernel (round-2 proven path).
// ---------------------------------------------------------------------------
__global__ __launch_bounds__(256, 3) void k_main_valu(
    const float* __restrict__ xsrc, const float* __restrict__ zadj,
    const float* __restrict__ W0, const float* __restrict__ B0,
    const float* __restrict__ W1, const float* __restrict__ B1,
    const float* __restrict__ W2, const float* __restrict__ B2,
    const float* __restrict__ W3, const float* __restrict__ B3,
    float* __restrict__ outp, int o_sS, int o_cS, int o_bS) {
    const int c = blockIdx.x;
    const int s = blockIdx.y;
    const int lane = threadIdx.x & 63;
    const int wave = threadIdx.x >> 6;

    const float* w0c = W0 + c * 2048;
    const float* w1c = W1 + c * 1024;
    const float* w2c = W2 + c * 1024;
    const float* w3c = W3 + c * 32;
    const float* b0c = B0 + c * 32;
    const float* b1c = B1 + c * 32;
    const float* b2c = B2 + c * 32;
    const float b3v = B3[c];
    const float* zc = zadj + s * 4096 + c;

#pragma unroll 1
    for (int bc = 0; bc < 2; ++bc) {
        const int b = wave * 128 + bc * 64 + lane;
        float h1[32], h2[32];
#pragma unroll
        for (int o = 0; o < 32; ++o) h1[o] = b0c[o];
#pragma unroll 8
        for (int i = 0; i < 64; ++i) {
            float hi = zc[i * 64] * xsrc[b * 64 + i];
#pragma unroll
            for (int o = 0; o < 32; ++o) h1[o] = fmaf(w0c[o * 64 + i], hi, h1[o]);
        }
#pragma unroll
        for (int o = 0; o < 32; ++o) { h1[o] = fmaxf(h1[o], 0.0f); h2[o] = b1c[o]; }
#pragma unroll 8
        for (int j = 0; j < 32; ++j) {
            float v = h1[j];
#pragma unroll
            for (int o = 0; o < 32; ++o) h2[o] = fmaf(w1c[o * 32 + j], v, h2[o]);
        }
#pragma unroll
        for (int o = 0; o < 32; ++o) { h2[o] = fmaxf(h2[o], 0.0f); h1[o] = b2c[o]; }
#pragma unroll 8
        for (int j = 0; j < 32; ++j) {
            float v = h2[j];
#pragma unroll
            for (int o = 0; o < 32; ++o) h1[o] = fmaf(w2c[o * 32 + j], v, h1[o]);
        }
        float a = b3v;
#pragma unroll
        for (int j = 0; j < 32; ++j) a = fmaf(w3c[j], fmaxf(h1[j], 0.0f), a);
        outp[s * o_sS + c * o_cS + b * o_bS] = a;
    }
}

// ---------------------------------------------------------------------------
// k_outT: transpose outT (s,c,b) -> out (b,s,c)
// ---------------------------------------------------------------------------
__global__ __launch_bounds__(256) void k_outT(const float* __restrict__ outT,
                                              float* __restrict__ out) {
    __shared__ float tile[64][65];
    const int bt = blockIdx.x;
    const int s = blockIdx.y;
    const int tid = threadIdx.x;
    const int r0 = tid >> 6, q = tid & 63;
#pragma unroll
    for (int rep = 0; rep < 16; ++rep) {
        int crow = rep * 4 + r0;
        tile[crow][q] = outT[(s * 64 + crow) * 512 + bt * 64 + q];
    }
    __syncthreads();
#pragma unroll
    for (int rep = 0; rep < 16; ++rep) {
        int brow = rep * 4 + r0;
        out[(bt * 64 + brow) * 4096 + s * 64 + q] = tile[q][brow];
    }
}

extern "C" void kernel_launch(void* const* d_in, const int* in_sizes, int n_in,
                              void* d_out, int out_size, void* d_ws, size_t ws_size,
                              hipStream_t stream) {
    const float* x  = (const float*)d_in[0];
    const float* z  = (const float*)d_in[1];
    const float* W0 = (const float*)d_in[2];
    const float* B0 = (const float*)d_in[3];
    const float* W1 = (const float*)d_in[4];
    const float* B1 = (const float*)d_in[5];
    const float* W2 = (const float*)d_in[6];
    const float* B2 = (const float*)d_in[7];
    const float* W3 = (const float*)d_in[8];
    const float* B3 = (const float*)d_in[9];

    float* out  = (float*)d_out;
    float* zadj = out + ZADJ_OFF;

    // workspace: outT | xf | w0f | w1f | w2f  (total 9,502,720 B)
    const size_t OT_B  = (size_t)S * D * BSZ * sizeof(float); // 8388608
    const size_t XF_B  = 4096 * 16;                           // 65536 (f16 single)
    const size_t W0F_B = 64 * 4 * 64 * 32;                    // 524288 (hi+lo 16B each)
    const size_t W1F_B = 64 * 4 * 2 * 64 * 8;                 // 262144
    const size_t W2F_B = W1F_B;
    const bool has_oT   = ws_size >= OT_B;
    const bool has_frag = ws_size >= OT_B + XF_B + W0F_B + W1F_B + W2F_B;

    char* wsb = (char*)d_ws;
    float* outT = (float*)wsb;
    uint4* xf   = (uint4*)(wsb + OT_B);
    uint4* w0f  = (uint4*)(wsb + OT_B + XF_B);
    uint2* w1f  = (uint2*)(wsb + OT_B + XF_B + W0F_B);
    uint2* w2f  = (uint2*)(wsb + OT_B + XF_B + W0F_B + W1F_B);

    if (has_frag) {
        hipLaunchKernelGGL(k_zadjprep, dim3(320), dim3(256), 0, stream,
                           z, zadj, x, W0, W1, W2, w0f, w1f, w2f, xf);
        hipLaunchKernelGGL(k_main_mfma, dim3(2, 64, 64), dim3(256), 0, stream,
                           xf, w0f, w1f, w2f, zadj,
                           B0, B1, B2, W3, B3, outT);
        hipLaunchKernelGGL(k_outT, dim3(8, S), dim3(256), 0, stream, outT, out);
    } else {
        hipLaunchKernelGGL(k_zadjprep, dim3(256), dim3(256), 0, stream,
                           z, zadj, x, W0, W1, W2,
                           (uint4*)nullptr, (uint2*)nullptr, (uint2*)nullptr,
                           (uint4*)nullptr);
        float* op = has_oT ? outT : out;
        const int o_sS = has_oT ? (64 * 512) : 64;
        const int o_cS = has_oT ? 512 : 1;
        const int o_bS = has_oT ? 1 : 4096;
        hipLaunchKernelGGL(k_main_valu, dim3(D, S), dim3(256), 0, stream,
                           x, zadj, W0, B0, W1, B1, W2, B2, W3, B3,
                           op, o_sS, o_cS, o_bS);
        if (has_oT)
            hipLaunchKernelGGL(k_outT, dim3(8, S), dim3(256), 0, stream, outT, out);
    }
}

// Round 6
// 119.408 us; speedup vs baseline: 8.8399x; 1.2221x over previous
//
#include <hip/hip_runtime.h>
#include <math.h>

#define D 64
#define S 64
#define BSZ 512
#define LTW 2016
#define ZROW 6112
#define OUT0_SIZE (BSZ * S * D)   // 2097152 floats
#define ZADJ_OFF  OUT0_SIZE

typedef float    f32x4 __attribute__((ext_vector_type(4)));
typedef _Float16 f16x8 __attribute__((ext_vector_type(8)));
typedef _Float16 f16x2 __attribute__((ext_vector_type(2)));

union V8 { f16x8 v; f16x2 h2[4]; uint4 u; };

__device__ __forceinline__ f16x2 pkrtz(float a, float b) {
    return __builtin_bit_cast(f16x2, __builtin_amdgcn_cvt_pkrtz(a, b));
}

// ---------------------------------------------------------------------------
// k_zadjprep: blocks 0..255 -> z_adj (s = blk>>2, jt = blk&3)
//             blocks 256..319 -> fragment prep for channel c = blk-256
// zadj stages register-tiled 4 j/thread: f32x4 wave-broadcast LDS reads,
// padded strides (zlt 65, T 20) -> conflict-free; LDS instr/thread 1024->256.
// ---------------------------------------------------------------------------
__global__ __launch_bounds__(256) void k_zadjprep(
    const float* __restrict__ z, float* __restrict__ zadj,
    const float* __restrict__ x,
    const float* __restrict__ W0, const float* __restrict__ W1,
    const float* __restrict__ W2,
    uint4* __restrict__ w0f, uint4* __restrict__ w1f,
    uint4* __restrict__ w2f, uint4* __restrict__ xf) {
    __shared__ float zp[4096];
    __shared__ float zlt[4160];   // 64 x 65 (padded)
    __shared__ float T[1280];     // 64 x 20 (16 used, padded)
    const int blk = blockIdx.x;
    const int tid = threadIdx.x;

    if (blk < 256) {
        const int s = blk >> 2, jt = blk & 3;
        const float* zs = z + (size_t)s * ZROW;
#pragma unroll
        for (int rep = 0; rep < 16; ++rep) {
            int idx = tid + rep * 256;
            zp[idx] = zs[LTW + idx];
        }
        for (int idx = tid; idx < 4160; idx += 256) zlt[idx] = 0.0f;
        __syncthreads();
        for (int k = tid; k < LTW; k += 256) {
            float kf = (float)k;
            int r = (int)((1.0f + sqrtf(1.0f + 8.0f * kf)) * 0.5f);
            while (r * (r - 1) / 2 > k) --r;
            while ((r + 1) * r / 2 <= k) ++r;
            int t = k - r * (r - 1) / 2;
            zlt[r * 65 + t] = zs[k];
        }
        __syncthreads();
        // stage 1: T[r][jj] = sum_t zlt[r][t] * zp[t][jt*16+jj], 4 jj/thread
        const int rr = tid & 63, wj = (tid >> 6) * 4;
        {
            f32x4 acc = {0.0f, 0.0f, 0.0f, 0.0f};
            for (int t = 0; t < 64; ++t) {
                float zl = zlt[rr * 65 + t];                       // 2-way, free
                f32x4 zpv = *(const f32x4*)&zp[t * 64 + jt * 16 + wj]; // bcast
#pragma unroll
                for (int q = 0; q < 4; ++q) acc[q] = fmaf(zl, zpv[q], acc[q]);
            }
            *(f32x4*)&T[rr * 20 + wj] = acc;
        }
        __syncthreads();
        // stage 2: zadj[i][j] = sum_r zp[r][i] * T[r][jj], 4 jj/thread
        {
            const int i = rr;
            f32x4 acc = {0.0f, 0.0f, 0.0f, 0.0f};
            for (int r = 0; r < 64; ++r) {
                float zv = zp[r * 64 + i];                         // 2-way, free
                f32x4 tv = *(const f32x4*)&T[r * 20 + wj];         // bcast
#pragma unroll
                for (int q = 0; q < 4; ++q) acc[q] = fmaf(zv, tv[q], acc[q]);
            }
            *(f32x4*)&zadj[(size_t)s * 4096 + i * 64 + jt * 16 + wj] = acc;
        }
    } else {
        const int c = blk - 256;
        const int sl = tid >> 6, ln = tid & 63;
        const int q = ln >> 4, l15 = ln & 15;
        // --- W0 A-frags (16x16x32 f16, single precision): A[m][k=ks*32+q*8+j]
        {
            int Mt = sl >> 1, ks = sl & 1;
            const float* src = W0 + c * 2048 + (Mt * 16 + l15) * 64 + ks * 32 + q * 8;
            V8 hv;
#pragma unroll
            for (int j = 0; j < 8; ++j) hv.v[j] = (_Float16)src[j];
            w0f[(size_t)(c * 4 + sl) * 64 + ln] = hv.u;
        }
        // --- W1/W2 A-frags (16x16x32 f16, PERMUTED K so in-lane C/D concat is
        //     a valid B operand): slot j -> k = (j>>2)*16 + q*4 + (j&3).
        //     waves 0-1: W1 (Mt=sl), waves 2-3: W2 (Mt=sl-2). hi/lo split.
        {
            const float* Wsrc = (sl < 2) ? W1 : W2;
            uint4* dstb = (sl < 2) ? w1f : w2f;
            int Mt = sl & 1;
            const float* srow = Wsrc + c * 1024 + (Mt * 16 + l15) * 32;
            V8 hi, lo;
#pragma unroll
            for (int j = 0; j < 8; ++j) {
                int k = ((j >> 2) << 4) + q * 4 + (j & 3);
                float e = srow[k];
                _Float16 h = (_Float16)e;
                hi.v[j] = h;
                lo.v[j] = (_Float16)(e - (float)h);
            }
            size_t base = ((size_t)(c * 2 + Mt) * 64 + ln) * 2;
            dstb[base] = hi.u;
            dstb[base + 1] = lo.u;
        }
        // --- x B-frags (16x16x32 f16): B[k=ks*32+q*8+j][n=bt*16+l15]
        if (tid < 64) {
            int f = c * 64 + tid;
            int fln = f & 63, ks = (f >> 6) & 1, bt = f >> 7;
            int n = bt * 16 + (fln & 15), i0 = ks * 32 + (fln >> 4) * 8;
            const float* src = x + n * 64 + i0;
            V8 hv;
#pragma unroll
            for (int j = 0; j < 8; ++j) hv.v[j] = (_Float16)src[j];
            xf[f] = hv.u;
        }
    }
}

// ---------------------------------------------------------------------------
// k_main_mfma: fused 4-layer per-channel MLP. Grid (bh=2, c=64, sg=16);
// each block processes 4 s with channel weights hoisted in registers.
// All layers 16x16x32 f16 (12 MFMA / Nt); layer transitions fully in-lane
// (relu + cvt_pkrtz, zero LDS / zero cross-lane). z folded into A of layer 0.
// ---------------------------------------------------------------------------
__global__ __launch_bounds__(256, 3) void k_main_mfma(
    const uint4* __restrict__ xf, const uint4* __restrict__ w0f,
    const uint4* __restrict__ w1f, const uint4* __restrict__ w2f,
    const float* __restrict__ zadj,
    const float* __restrict__ B0, const float* __restrict__ B1,
    const float* __restrict__ B2, const float* __restrict__ W3,
    const float* __restrict__ B3, float* __restrict__ outT) {
    const int bh = blockIdx.x;              // b-half (256 b's)
    const int c = blockIdx.y, sg = blockIdx.z;
    const int tid = threadIdx.x;
    const int wave = tid >> 6, lane = tid & 63;
    const int quad = lane >> 4;
    const int btbase = bh * 16 + wave * 4;  // 16-wide b-tiles

    // ---- hoisted channel weights
    V8 a0[2][2];                             // [Mt][ks], f16 single
#pragma unroll
    for (int Mt = 0; Mt < 2; ++Mt)
#pragma unroll
        for (int ks = 0; ks < 2; ++ks)
            a0[Mt][ks].u = w0f[(size_t)(c * 4 + Mt * 2 + ks) * 64 + lane];
    V8 a1h[2], a1l[2], a2h[2], a2l[2];       // [Mt], permuted-K hi/lo
#pragma unroll
    for (int Mt = 0; Mt < 2; ++Mt) {
        size_t base = ((size_t)(c * 2 + Mt) * 64 + lane) * 2;
        a1h[Mt].u = w1f[base];
        a1l[Mt].u = w1f[base + 1];
        a2h[Mt].u = w2f[base];
        a2l[Mt].u = w2f[base + 1];
    }
    // ---- biases / w3 (per-lane rows o = Mt*16 + quad*4 + r)
    f32x4 b0v[2], b1v[2], b2v[2], w3v[2];
#pragma unroll
    for (int Mt = 0; Mt < 2; ++Mt) {
        int off = c * 32 + Mt * 16 + quad * 4;
        b0v[Mt] = *(const f32x4*)(B0 + off);
        b1v[Mt] = *(const f32x4*)(B1 + off);
        b2v[Mt] = *(const f32x4*)(B2 + off);
        w3v[Mt] = *(const f32x4*)(W3 + off);
    }
    const float b3v = B3[c];

#pragma unroll 1
    for (int it = 0; it < 4; ++it) {
        const int s = sg * 4 + it;
        // ---- z (diag) for k = ks*32 + quad*8 + j, as f16 pairs
        f16x2 zvh[2][4];
#pragma unroll
        for (int ks = 0; ks < 2; ++ks) {
            const float* zp = zadj + (size_t)s * 4096 + (ks * 32 + quad * 8) * 64 + c;
            float zv[8];
#pragma unroll
            for (int j = 0; j < 8; ++j) zv[j] = zp[j * 64];
#pragma unroll
            for (int t = 0; t < 4; ++t)
                zvh[ks][t] = pkrtz(zv[2 * t], zv[2 * t + 1]);
        }
        // ---- scale layer-0 A by z (A[m][k] *= z[k])
        V8 a0s[2][2];
#pragma unroll
        for (int Mt = 0; Mt < 2; ++Mt)
#pragma unroll
            for (int ks = 0; ks < 2; ++ks)
#pragma unroll
                for (int t = 0; t < 4; ++t)
                    a0s[Mt][ks].h2[t] = a0[Mt][ks].h2[t] * zvh[ks][t];

        float red[4];
#pragma unroll
        for (int Nt = 0; Nt < 4; ++Nt) {
            // ---------- layer 0 ----------
            f32x4 acc0[2] = {b0v[0], b0v[1]};
#pragma unroll
            for (int ks = 0; ks < 2; ++ks) {
                V8 xv;
                xv.u = xf[(size_t)((btbase + Nt) * 2 + ks) * 64 + lane];
#pragma unroll
                for (int Mt = 0; Mt < 2; ++Mt)
                    acc0[Mt] = __builtin_amdgcn_mfma_f32_16x16x32_f16(
                        a0s[Mt][ks].v, xv.v, acc0[Mt], 0, 0, 0);
            }
            // ---------- transition 0->1 (in-lane concat, permuted-K B) ------
            V8 bb;
            bb.h2[0] = pkrtz(fmaxf(acc0[0][0], 0.0f), fmaxf(acc0[0][1], 0.0f));
            bb.h2[1] = pkrtz(fmaxf(acc0[0][2], 0.0f), fmaxf(acc0[0][3], 0.0f));
            bb.h2[2] = pkrtz(fmaxf(acc0[1][0], 0.0f), fmaxf(acc0[1][1], 0.0f));
            bb.h2[3] = pkrtz(fmaxf(acc0[1][2], 0.0f), fmaxf(acc0[1][3], 0.0f));
            // ---------- layer 1 ----------
            f32x4 acc1[2] = {b1v[0], b1v[1]};
#pragma unroll
            for (int Mt = 0; Mt < 2; ++Mt) {
                acc1[Mt] = __builtin_amdgcn_mfma_f32_16x16x32_f16(
                    a1h[Mt].v, bb.v, acc1[Mt], 0, 0, 0);
                acc1[Mt] = __builtin_amdgcn_mfma_f32_16x16x32_f16(
                    a1l[Mt].v, bb.v, acc1[Mt], 0, 0, 0);
            }
            // ---------- transition 1->2 ----------
            V8 cc;
            cc.h2[0] = pkrtz(fmaxf(acc1[0][0], 0.0f), fmaxf(acc1[0][1], 0.0f));
            cc.h2[1] = pkrtz(fmaxf(acc1[0][2], 0.0f), fmaxf(acc1[0][3], 0.0f));
            cc.h2[2] = pkrtz(fmaxf(acc1[1][0], 0.0f), fmaxf(acc1[1][1], 0.0f));
            cc.h2[3] = pkrtz(fmaxf(acc1[1][2], 0.0f), fmaxf(acc1[1][3], 0.0f));
            // ---------- layer 2 ----------
            f32x4 acc2[2] = {b2v[0], b2v[1]};
#pragma unroll
            for (int Mt = 0; Mt < 2; ++Mt) {
                acc2[Mt] = __builtin_amdgcn_mfma_f32_16x16x32_f16(
                    a2h[Mt].v, cc.v, acc2[Mt], 0, 0, 0);
                acc2[Mt] = __builtin_amdgcn_mfma_f32_16x16x32_f16(
                    a2l[Mt].v, cc.v, acc2[Mt], 0, 0, 0);
            }
            // ---------- layer 3 partial: relu(acc2) . w3 ----------
            float p = 0.0f;
#pragma unroll
            for (int Mt = 0; Mt < 2; ++Mt)
#pragma unroll
                for (int r = 0; r < 4; ++r)
                    p = fmaf(w3v[Mt][r], fmaxf(acc2[Mt][r], 0.0f), p);
            p += __shfl_xor(p, 16, 64);
            p += __shfl_xor(p, 32, 64);
            red[Nt] = p;
        }
        float outv = (quad & 2) ? ((quad & 1) ? red[3] : red[2])
                                : ((quad & 1) ? red[1] : red[0]);
        outv += b3v;
        outT[((size_t)s * 64 + c) * 512 + bh * 256 + tid] = outv;
    }
}

// ---------------------------------------------------------------------------
// Fallback VALU kernel (round-2 proven path).
// ---------------------------------------------------------------------------
__global__ __launch_bounds__(256, 3) void k_main_valu(
    const float* __restrict__ xsrc, const float* __restrict__ zadj,
    const float* __restrict__ W0, const float* __restrict__ B0,
    const float* __restrict__ W1, const float* __restrict__ B1,
    const float* __restrict__ W2, const float* __restrict__ B2,
    const float* __restrict__ W3, const float* __restrict__ B3,
    float* __restrict__ outp, int o_sS, int o_cS, int o_bS) {
    const int c = blockIdx.x;
    const int s = blockIdx.y;
    const int lane = threadIdx.x & 63;
    const int wave = threadIdx.x >> 6;

    const float* w0c = W0 + c * 2048;
    const float* w1c = W1 + c * 1024;
    const float* w2c = W2 + c * 1024;
    const float* w3c = W3 + c * 32;
    const float* b0c = B0 + c * 32;
    const float* b1c = B1 + c * 32;
    const float* b2c = B2 + c * 32;
    const float b3v = B3[c];
    const float* zc = zadj + s * 4096 + c;

#pragma unroll 1
    for (int bc = 0; bc < 2; ++bc) {
        const int b = wave * 128 + bc * 64 + lane;
        float h1[32], h2[32];
#pragma unroll
        for (int o = 0; o < 32; ++o) h1[o] = b0c[o];
#pragma unroll 8
        for (int i = 0; i < 64; ++i) {
            float hi = zc[i * 64] * xsrc[b * 64 + i];
#pragma unroll
            for (int o = 0; o < 32; ++o) h1[o] = fmaf(w0c[o * 64 + i], hi, h1[o]);
        }
#pragma unroll
        for (int o = 0; o < 32; ++o) { h1[o] = fmaxf(h1[o], 0.0f); h2[o] = b1c[o]; }
#pragma unroll 8
        for (int j = 0; j < 32; ++j) {
            float v = h1[j];
#pragma unroll
            for (int o = 0; o < 32; ++o) h2[o] = fmaf(w1c[o * 32 + j], v, h2[o]);
        }
#pragma unroll
        for (int o = 0; o < 32; ++o) { h2[o] = fmaxf(h2[o], 0.0f); h1[o] = b2c[o]; }
#pragma unroll 8
        for (int j = 0; j < 32; ++j) {
            float v = h2[j];
#pragma unroll
            for (int o = 0; o < 32; ++o) h1[o] = fmaf(w2c[o * 32 + j], v, h1[o]);
        }
        float a = b3v;
#pragma unroll
        for (int j = 0; j < 32; ++j) a = fmaf(w3c[j], fmaxf(h1[j], 0.0f), a);
        outp[s * o_sS + c * o_cS + b * o_bS] = a;
    }
}

// ---------------------------------------------------------------------------
// k_outT: transpose outT (s,c,b) -> out (b,s,c)
// ---------------------------------------------------------------------------
__global__ __launch_bounds__(256) void k_outT(const float* __restrict__ outT,
                                              float* __restrict__ out) {
    __shared__ float tile[64][65];
    const int bt = blockIdx.x;
    const int s = blockIdx.y;
    const int tid = threadIdx.x;
    const int r0 = tid >> 6, q = tid & 63;
#pragma unroll
    for (int rep = 0; rep < 16; ++rep) {
        int crow = rep * 4 + r0;
        tile[crow][q] = outT[(s * 64 + crow) * 512 + bt * 64 + q];
    }
    __syncthreads();
#pragma unroll
    for (int rep = 0; rep < 16; ++rep) {
        int brow = rep * 4 + r0;
        out[(bt * 64 + brow) * 4096 + s * 64 + q] = tile[q][brow];
    }
}

extern "C" void kernel_launch(void* const* d_in, const int* in_sizes, int n_in,
                              void* d_out, int out_size, void* d_ws, size_t ws_size,
                              hipStream_t stream) {
    const float* x  = (const float*)d_in[0];
    const float* z  = (const float*)d_in[1];
    const float* W0 = (const float*)d_in[2];
    const float* B0 = (const float*)d_in[3];
    const float* W1 = (const float*)d_in[4];
    const float* B1 = (const float*)d_in[5];
    const float* W2 = (const float*)d_in[6];
    const float* B2 = (const float*)d_in[7];
    const float* W3 = (const float*)d_in[8];
    const float* B3 = (const float*)d_in[9];

    float* out  = (float*)d_out;
    float* zadj = out + ZADJ_OFF;

    // workspace: outT | xf | w0f | w1f | w2f
    const size_t OT_B  = (size_t)S * D * BSZ * sizeof(float); // 8388608
    const size_t XF_B  = 4096 * 16;                           // 65536
    const size_t W0F_B = (size_t)64 * 4 * 64 * 16;            // 262144
    const size_t W1F_B = (size_t)64 * 2 * 64 * 2 * 16;        // 262144
    const size_t W2F_B = W1F_B;
    const bool has_oT   = ws_size >= OT_B;
    const bool has_frag = ws_size >= OT_B + XF_B + W0F_B + W1F_B + W2F_B;

    char* wsb = (char*)d_ws;
    float* outT = (float*)wsb;
    uint4* xf   = (uint4*)(wsb + OT_B);
    uint4* w0f  = (uint4*)(wsb + OT_B + XF_B);
    uint4* w1f  = (uint4*)(wsb + OT_B + XF_B + W0F_B);
    uint4* w2f  = (uint4*)(wsb + OT_B + XF_B + W0F_B + W1F_B);

    if (has_frag) {
        hipLaunchKernelGGL(k_zadjprep, dim3(320), dim3(256), 0, stream,
                           z, zadj, x, W0, W1, W2, w0f, w1f, w2f, xf);
        hipLaunchKernelGGL(k_main_mfma, dim3(2, 64, 16), dim3(256), 0, stream,
                           xf, w0f, w1f, w2f, zadj,
                           B0, B1, B2, W3, B3, outT);
        hipLaunchKernelGGL(k_outT, dim3(8, S), dim3(256), 0, stream, outT, out);
    } else {
        hipLaunchKernelGGL(k_zadjprep, dim3(256), dim3(256), 0, stream,
                           z, zadj, x, W0, W1, W2,
                           (uint4*)nullptr, (uint4*)nullptr, (uint4*)nullptr,
                           (uint4*)nullptr);
        float* op = has_oT ? outT : out;
        const int o_sS = has_oT ? (64 * 512) : 64;
        const int o_cS = has_oT ? 512 : 1;
        const int o_bS = has_oT ? 1 : 4096;
        hipLaunchKernelGGL(k_main_valu, dim3(D, S), dim3(256), 0, stream,
                           x, zadj, W0, B0, W1, B1, W2, B2, W3, B3,
                           op, o_sS, o_cS, o_bS);
        if (has_oT)
            hipLaunchKernelGGL(k_outT, dim3(8, S), dim3(256), 0, stream, outT, out);
    }
}

// Round 7
// 114.261 us; speedup vs baseline: 9.2382x; 1.0451x over previous
//
#include <hip/hip_runtime.h>
#include <math.h>

#define D 64
#define S 64
#define BSZ 512
#define LTW 2016
#define ZROW 6112
#define OUT0_SIZE (BSZ * S * D)   // 2097152 floats
#define ZADJ_OFF  OUT0_SIZE

typedef float    f32x4 __attribute__((ext_vector_type(4)));
typedef _Float16 f16x8 __attribute__((ext_vector_type(8)));
typedef _Float16 f16x2 __attribute__((ext_vector_type(2)));

union V8 { f16x8 v; f16x2 h2[4]; uint4 u; };

__device__ __forceinline__ f16x2 pkrtz(float a, float b) {
    return __builtin_bit_cast(f16x2, __builtin_amdgcn_cvt_pkrtz(a, b));
}

// ---------------------------------------------------------------------------
// k_zadjprep: blocks 0..255 -> z_adj (s = blk>>2, jt = blk&3), also writes
//             transposed zadjT[s][j][i] (coalesced) when zt != nullptr.
//             blocks 256..319 -> fragment prep for channel c = blk-256.
// ---------------------------------------------------------------------------
__global__ __launch_bounds__(256) void k_zadjprep(
    const float* __restrict__ z, float* __restrict__ zadj,
    float* __restrict__ zt,
    const float* __restrict__ x,
    const float* __restrict__ W0, const float* __restrict__ W1,
    const float* __restrict__ W2,
    uint4* __restrict__ w0f, uint4* __restrict__ w1f,
    uint4* __restrict__ w2f, uint4* __restrict__ xf) {
    __shared__ float zp[4096];
    __shared__ float zlt[4160];   // 64 x 65 (padded)
    __shared__ float T[1280];     // 64 x 20 (16 used, padded)
    const int blk = blockIdx.x;
    const int tid = threadIdx.x;

    if (blk < 256) {
        const int s = blk >> 2, jt = blk & 3;
        const float* zs = z + (size_t)s * ZROW;
#pragma unroll
        for (int rep = 0; rep < 16; ++rep) {
            int idx = tid + rep * 256;
            zp[idx] = zs[LTW + idx];
        }
        for (int idx = tid; idx < 4160; idx += 256) zlt[idx] = 0.0f;
        __syncthreads();
        for (int k = tid; k < LTW; k += 256) {
            float kf = (float)k;
            int r = (int)((1.0f + sqrtf(1.0f + 8.0f * kf)) * 0.5f);
            while (r * (r - 1) / 2 > k) --r;
            while ((r + 1) * r / 2 <= k) ++r;
            int t = k - r * (r - 1) / 2;
            zlt[r * 65 + t] = zs[k];
        }
        __syncthreads();
        // stage 1: T[r][jj] = sum_t zlt[r][t] * zp[t][jt*16+jj], 4 jj/thread
        const int rr = tid & 63, wj = (tid >> 6) * 4;
        {
            f32x4 acc = {0.0f, 0.0f, 0.0f, 0.0f};
            for (int t = 0; t < 64; ++t) {
                float zl = zlt[rr * 65 + t];                       // 2-way, free
                f32x4 zpv = *(const f32x4*)&zp[t * 64 + jt * 16 + wj]; // bcast
#pragma unroll
                for (int q = 0; q < 4; ++q) acc[q] = fmaf(zl, zpv[q], acc[q]);
            }
            *(f32x4*)&T[rr * 20 + wj] = acc;
        }
        __syncthreads();
        // stage 2: zadj[i][j] = sum_r zp[r][i] * T[r][jj], 4 jj/thread
        {
            const int i = rr;
            f32x4 acc = {0.0f, 0.0f, 0.0f, 0.0f};
            for (int r = 0; r < 64; ++r) {
                float zv = zp[r * 64 + i];                         // 2-way, free
                f32x4 tv = *(const f32x4*)&T[r * 20 + wj];         // bcast
#pragma unroll
                for (int q = 0; q < 4; ++q) acc[q] = fmaf(zv, tv[q], acc[q]);
            }
            *(f32x4*)&zadj[(size_t)s * 4096 + i * 64 + jt * 16 + wj] = acc;
            if (zt) {
                // transposed copy: zt[s][j][i] = zadj[s][i][j]; coalesced in i
#pragma unroll
                for (int q = 0; q < 4; ++q)
                    zt[(size_t)s * 4096 + (jt * 16 + wj + q) * 64 + i] = acc[q];
            }
        }
    } else {
        const int c = blk - 256;
        const int sl = tid >> 6, ln = tid & 63;
        const int q = ln >> 4, l15 = ln & 15;
        // --- W0 A-frags (16x16x32 f16, single precision): A[m][k=ks*32+q*8+j]
        {
            int Mt = sl >> 1, ks = sl & 1;
            const float* src = W0 + c * 2048 + (Mt * 16 + l15) * 64 + ks * 32 + q * 8;
            V8 hv;
#pragma unroll
            for (int j = 0; j < 8; ++j) hv.v[j] = (_Float16)src[j];
            w0f[(size_t)(c * 4 + sl) * 64 + ln] = hv.u;
        }
        // --- W1/W2 A-frags (16x16x32 f16, PERMUTED K so in-lane C/D concat is
        //     a valid B operand): slot j -> k = (j>>2)*16 + q*4 + (j&3).
        //     waves 0-1: W1 (Mt=sl), waves 2-3: W2 (Mt=sl-2). Single f16.
        {
            const float* Wsrc = (sl < 2) ? W1 : W2;
            uint4* dstb = (sl < 2) ? w1f : w2f;
            int Mt = sl & 1;
            const float* srow = Wsrc + c * 1024 + (Mt * 16 + l15) * 32;
            V8 hv;
#pragma unroll
            for (int j = 0; j < 8; ++j) {
                int k = ((j >> 2) << 4) + q * 4 + (j & 3);
                hv.v[j] = (_Float16)srow[k];
            }
            dstb[(size_t)(c * 2 + Mt) * 64 + ln] = hv.u;
        }
        // --- x B-frags (16x16x32 f16): B[k=ks*32+q*8+j][n=bt*16+l15]
        if (tid < 64) {
            int f = c * 64 + tid;
            int fln = f & 63, ks = (f >> 6) & 1, bt = f >> 7;
            int n = bt * 16 + (fln & 15), i0 = ks * 32 + (fln >> 4) * 8;
            const float* src = x + n * 64 + i0;
            V8 hv;
#pragma unroll
            for (int j = 0; j < 8; ++j) hv.v[j] = (_Float16)src[j];
            xf[f] = hv.u;
        }
    }
}

// ---------------------------------------------------------------------------
// k_main_mfma: fused 4-layer per-channel MLP. Grid (bh=2, c=64, sg=16);
// each block processes 4 s with channel weights hoisted in registers.
// All layers 16x16x32 f16, 8 MFMA / Nt (W1/W2 single-precision f16 —
// lo terms dropped; error budget ~2^-11 rel, same order as activation
// rounding). Transitions fully in-lane. z folded into A of layer 0.
// ZT: read z column via compact zadjT (4 broadcast dwordx4) vs 16 strided.
// ---------------------------------------------------------------------------
template <bool ZT>
__global__ __launch_bounds__(256, 4) void k_main_mfma(
    const uint4* __restrict__ xf, const uint4* __restrict__ w0f,
    const uint4* __restrict__ w1f, const uint4* __restrict__ w2f,
    const float* __restrict__ zadj, const float* __restrict__ zadjT,
    const float* __restrict__ B0, const float* __restrict__ B1,
    const float* __restrict__ B2, const float* __restrict__ W3,
    const float* __restrict__ B3, float* __restrict__ outT) {
    const int bh = blockIdx.x;              // b-half (256 b's)
    const int c = blockIdx.y, sg = blockIdx.z;
    const int tid = threadIdx.x;
    const int wave = tid >> 6, lane = tid & 63;
    const int quad = lane >> 4;
    const int btbase = bh * 16 + wave * 4;  // 16-wide b-tiles

    // ---- hoisted channel weights
    V8 a0[2][2];                             // [Mt][ks], f16 single
#pragma unroll
    for (int Mt = 0; Mt < 2; ++Mt)
#pragma unroll
        for (int ks = 0; ks < 2; ++ks)
            a0[Mt][ks].u = w0f[(size_t)(c * 4 + Mt * 2 + ks) * 64 + lane];
    V8 a1[2], a2[2];                         // [Mt], permuted-K single f16
#pragma unroll
    for (int Mt = 0; Mt < 2; ++Mt) {
        a1[Mt].u = w1f[(size_t)(c * 2 + Mt) * 64 + lane];
        a2[Mt].u = w2f[(size_t)(c * 2 + Mt) * 64 + lane];
    }
    // ---- biases / w3 (per-lane rows o = Mt*16 + quad*4 + r)
    f32x4 b0v[2], b1v[2], b2v[2], w3v[2];
#pragma unroll
    for (int Mt = 0; Mt < 2; ++Mt) {
        int off = c * 32 + Mt * 16 + quad * 4;
        b0v[Mt] = *(const f32x4*)(B0 + off);
        b1v[Mt] = *(const f32x4*)(B1 + off);
        b2v[Mt] = *(const f32x4*)(B2 + off);
        w3v[Mt] = *(const f32x4*)(W3 + off);
    }
    const float b3v = B3[c];

#pragma unroll 1
    for (int it = 0; it < 4; ++it) {
        const int s = sg * 4 + it;
        // ---- z (diag) for k = ks*32 + quad*8 + j, as f16 pairs
        f16x2 zvh[2][4];
        if (ZT) {
            const f32x4* ztp = (const f32x4*)(zadjT + (size_t)s * 4096 + c * 64);
            f32x4 zq[4];
            zq[0] = ztp[quad * 2];
            zq[1] = ztp[quad * 2 + 1];
            zq[2] = ztp[8 + quad * 2];
            zq[3] = ztp[8 + quad * 2 + 1];
#pragma unroll
            for (int ks = 0; ks < 2; ++ks)
#pragma unroll
                for (int t = 0; t < 4; ++t) {
                    const f32x4& v = zq[ks * 2 + (t >> 1)];
                    zvh[ks][t] = pkrtz(v[(t & 1) * 2], v[(t & 1) * 2 + 1]);
                }
        } else {
#pragma unroll
            for (int ks = 0; ks < 2; ++ks) {
                const float* zp = zadj + (size_t)s * 4096 + (ks * 32 + quad * 8) * 64 + c;
                float zv[8];
#pragma unroll
                for (int j = 0; j < 8; ++j) zv[j] = zp[j * 64];
#pragma unroll
                for (int t = 0; t < 4; ++t)
                    zvh[ks][t] = pkrtz(zv[2 * t], zv[2 * t + 1]);
            }
        }
        // ---- scale layer-0 A by z (A[m][k] *= z[k])
        V8 a0s[2][2];
#pragma unroll
        for (int Mt = 0; Mt < 2; ++Mt)
#pragma unroll
            for (int ks = 0; ks < 2; ++ks)
#pragma unroll
                for (int t = 0; t < 4; ++t)
                    a0s[Mt][ks].h2[t] = a0[Mt][ks].h2[t] * zvh[ks][t];

        float red[4];
#pragma unroll
        for (int Nt = 0; Nt < 4; ++Nt) {
            // ---------- layer 0 ----------
            f32x4 acc0[2] = {b0v[0], b0v[1]};
#pragma unroll
            for (int ks = 0; ks < 2; ++ks) {
                V8 xv;
                xv.u = xf[(size_t)((btbase + Nt) * 2 + ks) * 64 + lane];
#pragma unroll
                for (int Mt = 0; Mt < 2; ++Mt)
                    acc0[Mt] = __builtin_amdgcn_mfma_f32_16x16x32_f16(
                        a0s[Mt][ks].v, xv.v, acc0[Mt], 0, 0, 0);
            }
            // ---------- transition 0->1 (in-lane concat, permuted-K B) ------
            V8 bb;
            bb.h2[0] = pkrtz(fmaxf(acc0[0][0], 0.0f), fmaxf(acc0[0][1], 0.0f));
            bb.h2[1] = pkrtz(fmaxf(acc0[0][2], 0.0f), fmaxf(acc0[0][3], 0.0f));
            bb.h2[2] = pkrtz(fmaxf(acc0[1][0], 0.0f), fmaxf(acc0[1][1], 0.0f));
            bb.h2[3] = pkrtz(fmaxf(acc0[1][2], 0.0f), fmaxf(acc0[1][3], 0.0f));
            // ---------- layer 1 ----------
            f32x4 acc1[2] = {b1v[0], b1v[1]};
#pragma unroll
            for (int Mt = 0; Mt < 2; ++Mt)
                acc1[Mt] = __builtin_amdgcn_mfma_f32_16x16x32_f16(
                    a1[Mt].v, bb.v, acc1[Mt], 0, 0, 0);
            // ---------- transition 1->2 ----------
            V8 cc;
            cc.h2[0] = pkrtz(fmaxf(acc1[0][0], 0.0f), fmaxf(acc1[0][1], 0.0f));
            cc.h2[1] = pkrtz(fmaxf(acc1[0][2], 0.0f), fmaxf(acc1[0][3], 0.0f));
            cc.h2[2] = pkrtz(fmaxf(acc1[1][0], 0.0f), fmaxf(acc1[1][1], 0.0f));
            cc.h2[3] = pkrtz(fmaxf(acc1[1][2], 0.0f), fmaxf(acc1[1][3], 0.0f));
            // ---------- layer 2 ----------
            f32x4 acc2[2] = {b2v[0], b2v[1]};
#pragma unroll
            for (int Mt = 0; Mt < 2; ++Mt)
                acc2[Mt] = __builtin_amdgcn_mfma_f32_16x16x32_f16(
                    a2[Mt].v, cc.v, acc2[Mt], 0, 0, 0);
            // ---------- layer 3 partial: relu(acc2) . w3 ----------
            float p = 0.0f;
#pragma unroll
            for (int Mt = 0; Mt < 2; ++Mt)
#pragma unroll
                for (int r = 0; r < 4; ++r)
                    p = fmaf(w3v[Mt][r], fmaxf(acc2[Mt][r], 0.0f), p);
            p += __shfl_xor(p, 16, 64);
            p += __shfl_xor(p, 32, 64);
            red[Nt] = p;
        }
        float outv = (quad & 2) ? ((quad & 1) ? red[3] : red[2])
                                : ((quad & 1) ? red[1] : red[0]);
        outv += b3v;
        outT[((size_t)s * 64 + c) * 512 + bh * 256 + tid] = outv;
    }
}

// ---------------------------------------------------------------------------
// Fallback VALU kernel (round-2 proven path).
// ---------------------------------------------------------------------------
__global__ __launch_bounds__(256, 3) void k_main_valu(
    const float* __restrict__ xsrc, const float* __restrict__ zadj,
    const float* __restrict__ W0, const float* __restrict__ B0,
    const float* __restrict__ W1, const float* __restrict__ B1,
    const float* __restrict__ W2, const float* __restrict__ B2,
    const float* __restrict__ W3, const float* __restrict__ B3,
    float* __restrict__ outp, int o_sS, int o_cS, int o_bS) {
    const int c = blockIdx.x;
    const int s = blockIdx.y;
    const int lane = threadIdx.x & 63;
    const int wave = threadIdx.x >> 6;

    const float* w0c = W0 + c * 2048;
    const float* w1c = W1 + c * 1024;
    const float* w2c = W2 + c * 1024;
    const float* w3c = W3 + c * 32;
    const float* b0c = B0 + c * 32;
    const float* b1c = B1 + c * 32;
    const float* b2c = B2 + c * 32;
    const float b3v = B3[c];
    const float* zc = zadj + s * 4096 + c;

#pragma unroll 1
    for (int bc = 0; bc < 2; ++bc) {
        const int b = wave * 128 + bc * 64 + lane;
        float h1[32], h2[32];
#pragma unroll
        for (int o = 0; o < 32; ++o) h1[o] = b0c[o];
#pragma unroll 8
        for (int i = 0; i < 64; ++i) {
            float hi = zc[i * 64] * xsrc[b * 64 + i];
#pragma unroll
            for (int o = 0; o < 32; ++o) h1[o] = fmaf(w0c[o * 64 + i], hi, h1[o]);
        }
#pragma unroll
        for (int o = 0; o < 32; ++o) { h1[o] = fmaxf(h1[o], 0.0f); h2[o] = b1c[o]; }
#pragma unroll 8
        for (int j = 0; j < 32; ++j) {
            float v = h1[j];
#pragma unroll
            for (int o = 0; o < 32; ++o) h2[o] = fmaf(w1c[o * 32 + j], v, h2[o]);
        }
#pragma unroll
        for (int o = 0; o < 32; ++o) { h2[o] = fmaxf(h2[o], 0.0f); h1[o] = b2c[o]; }
#pragma unroll 8
        for (int j = 0; j < 32; ++j) {
            float v = h2[j];
#pragma unroll
            for (int o = 0; o < 32; ++o) h1[o] = fmaf(w2c[o * 32 + j], v, h1[o]);
        }
        float a = b3v;
#pragma unroll
        for (int j = 0; j < 32; ++j) a = fmaf(w3c[j], fmaxf(h1[j], 0.0f), a);
        outp[s * o_sS + c * o_cS + b * o_bS] = a;
    }
}

// ---------------------------------------------------------------------------
// k_outT: transpose outT (s,c,b) -> out (b,s,c)
// ---------------------------------------------------------------------------
__global__ __launch_bounds__(256) void k_outT(const float* __restrict__ outT,
                                              float* __restrict__ out) {
    __shared__ float tile[64][65];
    const int bt = blockIdx.x;
    const int s = blockIdx.y;
    const int tid = threadIdx.x;
    const int r0 = tid >> 6, q = tid & 63;
#pragma unroll
    for (int rep = 0; rep < 16; ++rep) {
        int crow = rep * 4 + r0;
        tile[crow][q] = outT[(s * 64 + crow) * 512 + bt * 64 + q];
    }
    __syncthreads();
#pragma unroll
    for (int rep = 0; rep < 16; ++rep) {
        int brow = rep * 4 + r0;
        out[(bt * 64 + brow) * 4096 + s * 64 + q] = tile[q][brow];
    }
}

extern "C" void kernel_launch(void* const* d_in, const int* in_sizes, int n_in,
                              void* d_out, int out_size, void* d_ws, size_t ws_size,
                              hipStream_t stream) {
    const float* x  = (const float*)d_in[0];
    const float* z  = (const float*)d_in[1];
    const float* W0 = (const float*)d_in[2];
    const float* B0 = (const float*)d_in[3];
    const float* W1 = (const float*)d_in[4];
    const float* B1 = (const float*)d_in[5];
    const float* W2 = (const float*)d_in[6];
    const float* B2 = (const float*)d_in[7];
    const float* W3 = (const float*)d_in[8];
    const float* B3 = (const float*)d_in[9];

    float* out  = (float*)d_out;
    float* zadj = out + ZADJ_OFF;

    // workspace: outT | xf | w0f | w1f | w2f | zadjT
    const size_t OT_B  = (size_t)S * D * BSZ * sizeof(float); // 8388608
    const size_t XF_B  = 4096 * 16;                           // 65536
    const size_t W0F_B = (size_t)64 * 4 * 64 * 16;            // 262144
    const size_t W1F_B = (size_t)64 * 2 * 64 * 16;            // 131072
    const size_t W2F_B = W1F_B;
    const size_t ZT_B  = (size_t)S * 4096 * sizeof(float);    // 1048576
    const size_t FRAG_END = OT_B + XF_B + W0F_B + W1F_B + W2F_B;
    const bool has_oT   = ws_size >= OT_B;
    const bool has_frag = ws_size >= FRAG_END;
    const bool has_zt   = ws_size >= FRAG_END + ZT_B;

    char* wsb = (char*)d_ws;
    float* outT  = (float*)wsb;
    uint4* xf    = (uint4*)(wsb + OT_B);
    uint4* w0f   = (uint4*)(wsb + OT_B + XF_B);
    uint4* w1f   = (uint4*)(wsb + OT_B + XF_B + W0F_B);
    uint4* w2f   = (uint4*)(wsb + OT_B + XF_B + W0F_B + W1F_B);
    float* zadjT = (float*)(wsb + FRAG_END);

    if (has_frag) {
        hipLaunchKernelGGL(k_zadjprep, dim3(320), dim3(256), 0, stream,
                           z, zadj, has_zt ? zadjT : (float*)nullptr,
                           x, W0, W1, W2, w0f, w1f, w2f, xf);
        if (has_zt)
            hipLaunchKernelGGL((k_main_mfma<true>), dim3(2, 64, 16), dim3(256),
                               0, stream, xf, w0f, w1f, w2f, zadj, zadjT,
                               B0, B1, B2, W3, B3, outT);
        else
            hipLaunchKernelGGL((k_main_mfma<false>), dim3(2, 64, 16), dim3(256),
                               0, stream, xf, w0f, w1f, w2f, zadj, zadjT,
                               B0, B1, B2, W3, B3, outT);
        hipLaunchKernelGGL(k_outT, dim3(8, S), dim3(256), 0, stream, outT, out);
    } else {
        hipLaunchKernelGGL(k_zadjprep, dim3(256), dim3(256), 0, stream,
                           z, zadj, (float*)nullptr, x, W0, W1, W2,
                           (uint4*)nullptr, (uint4*)nullptr, (uint4*)nullptr,
                           (uint4*)nullptr);
        float* op = has_oT ? outT : out;
        const int o_sS = has_oT ? (64 * 512) : 64;
        const int o_cS = has_oT ? 512 : 1;
        const int o_bS = has_oT ? 1 : 4096;
        hipLaunchKernelGGL(k_main_valu, dim3(D, S), dim3(256), 0, stream,
                           x, zadj, W0, B0, W1, B1, W2, B2, W3, B3,
                           op, o_sS, o_cS, o_bS);
        if (has_oT)
            hipLaunchKernelGGL(k_outT, dim3(8, S), dim3(256), 0, stream, outT, out);
    }
}

// Round 8
// 109.560 us; speedup vs baseline: 9.6346x; 1.0429x over previous
//
#include <hip/hip_runtime.h>
#include <math.h>

#define D 64
#define S 64
#define BSZ 512
#define LTW 2016
#define ZROW 6112
#define OUT0_SIZE (BSZ * S * D)   // 2097152 floats
#define ZADJ_OFF  OUT0_SIZE

typedef float    f32x4 __attribute__((ext_vector_type(4)));
typedef _Float16 f16x8 __attribute__((ext_vector_type(8)));
typedef _Float16 f16x2 __attribute__((ext_vector_type(2)));

union V8 { f16x8 v; f16x2 h2[4]; uint4 u; };

__device__ __forceinline__ f16x2 pkrtz(float a, float b) {
    return __builtin_bit_cast(f16x2, __builtin_amdgcn_cvt_pkrtz(a, b));
}
__device__ __forceinline__ f16x8 relu8(f16x8 a) {
#if __has_builtin(__builtin_elementwise_max)
    return __builtin_elementwise_max(a, (f16x8)0);   // v_pk_max_f16 x4
#else
    f16x8 r;
#pragma unroll
    for (int i = 0; i < 8; ++i) r[i] = a[i] > (_Float16)0 ? a[i] : (_Float16)0;
    return r;
#endif
}

// ---------------------------------------------------------------------------
// k_zadjprep: blocks 0..255 -> z_adj (s = blk>>2, jt = blk&3), plus
//             transposed zadjT[s][j][i] when zt != nullptr.
//             blocks 256..319 -> fragment prep for channel c = blk-256.
// ---------------------------------------------------------------------------
__global__ __launch_bounds__(256) void k_zadjprep(
    const float* __restrict__ z, float* __restrict__ zadj,
    float* __restrict__ zt,
    const float* __restrict__ x,
    const float* __restrict__ W0, const float* __restrict__ W1,
    const float* __restrict__ W2,
    uint4* __restrict__ w0f, uint4* __restrict__ w1f,
    uint4* __restrict__ w2f, uint4* __restrict__ xf) {
    __shared__ float zp[4096];
    __shared__ float zlt[4160];   // 64 x 65 (padded)
    __shared__ float T[1280];     // 64 x 20 (16 used, padded)
    const int blk = blockIdx.x;
    const int tid = threadIdx.x;

    if (blk < 256) {
        const int s = blk >> 2, jt = blk & 3;
        const float* zs = z + (size_t)s * ZROW;
#pragma unroll
        for (int rep = 0; rep < 16; ++rep) {
            int idx = tid + rep * 256;
            zp[idx] = zs[LTW + idx];
        }
        for (int idx = tid; idx < 4160; idx += 256) zlt[idx] = 0.0f;
        __syncthreads();
        for (int k = tid; k < LTW; k += 256) {
            float kf = (float)k;
            int r = (int)((1.0f + sqrtf(1.0f + 8.0f * kf)) * 0.5f);
            while (r * (r - 1) / 2 > k) --r;
            while ((r + 1) * r / 2 <= k) ++r;
            int t = k - r * (r - 1) / 2;
            zlt[r * 65 + t] = zs[k];
        }
        __syncthreads();
        // stage 1: T[r][jj] = sum_t zlt[r][t] * zp[t][jt*16+jj], 4 jj/thread
        const int rr = tid & 63, wj = (tid >> 6) * 4;
        {
            f32x4 acc = {0.0f, 0.0f, 0.0f, 0.0f};
#pragma unroll 8
            for (int t = 0; t < 64; ++t) {
                float zl = zlt[rr * 65 + t];                       // 2-way, free
                f32x4 zpv = *(const f32x4*)&zp[t * 64 + jt * 16 + wj]; // bcast
#pragma unroll
                for (int q = 0; q < 4; ++q) acc[q] = fmaf(zl, zpv[q], acc[q]);
            }
            *(f32x4*)&T[rr * 20 + wj] = acc;
        }
        __syncthreads();
        // stage 2: zadj[i][j] = sum_r zp[r][i] * T[r][jj], 4 jj/thread
        {
            const int i = rr;
            f32x4 acc = {0.0f, 0.0f, 0.0f, 0.0f};
#pragma unroll 8
            for (int r = 0; r < 64; ++r) {
                float zv = zp[r * 64 + i];                         // 2-way, free
                f32x4 tv = *(const f32x4*)&T[r * 20 + wj];         // bcast
#pragma unroll
                for (int q = 0; q < 4; ++q) acc[q] = fmaf(zv, tv[q], acc[q]);
            }
            *(f32x4*)&zadj[(size_t)s * 4096 + i * 64 + jt * 16 + wj] = acc;
            if (zt) {
#pragma unroll
                for (int q = 0; q < 4; ++q)
                    zt[(size_t)s * 4096 + (jt * 16 + wj + q) * 64 + i] = acc[q];
            }
        }
    } else {
        const int c = blk - 256;
        const int sl = tid >> 6, ln = tid & 63;
        const int q = ln >> 4, l15 = ln & 15;
        // --- W0 A-frags (16x16x32 f16): A[m][k=ks*32+q*8+j]
        {
            int Mt = sl >> 1, ks = sl & 1;
            const float* src = W0 + c * 2048 + (Mt * 16 + l15) * 64 + ks * 32 + q * 8;
            V8 hv;
#pragma unroll
            for (int j = 0; j < 8; ++j) hv.v[j] = (_Float16)src[j];
            w0f[(size_t)(c * 4 + sl) * 64 + ln] = hv.u;
        }
        // --- W1/W2 A-frags (16x16x32 f16, PERMUTED K): slot j -> k=(j>>2)*16+q*4+(j&3)
        {
            const float* Wsrc = (sl < 2) ? W1 : W2;
            uint4* dstb = (sl < 2) ? w1f : w2f;
            int Mt = sl & 1;
            const float* srow = Wsrc + c * 1024 + (Mt * 16 + l15) * 32;
            V8 hv;
#pragma unroll
            for (int j = 0; j < 8; ++j) {
                int k = ((j >> 2) << 4) + q * 4 + (j & 3);
                hv.v[j] = (_Float16)srow[k];
            }
            dstb[(size_t)(c * 2 + Mt) * 64 + ln] = hv.u;
        }
        // --- x B-frags (16x16x32 f16): B[k=ks*32+q*8+j][n=bt*16+l15]
        if (tid < 64) {
            int f = c * 64 + tid;
            int fln = f & 63, ks = (f >> 6) & 1, bt = f >> 7;
            int n = bt * 16 + (fln & 15), i0 = ks * 32 + (fln >> 4) * 8;
            const float* src = x + n * 64 + i0;
            V8 hv;
#pragma unroll
            for (int j = 0; j < 8; ++j) hv.v[j] = (_Float16)src[j];
            xf[f] = hv.u;
        }
    }
}

// ---------------------------------------------------------------------------
// k_main_mfma: fused 4-layer per-channel MLP. Grid (bh=2, c=64, sg=16);
// 4 s per block; channel weights AND x-fragments (s-invariant!) hoisted in
// registers -> the s-loop's only global traffic is 4 z dwordx4 loads.
// All layers 16x16x32 f16, 8 MFMA/Nt; transitions in-lane (pkrtz + pk_max).
// ---------------------------------------------------------------------------
template <bool ZT>
__global__ __launch_bounds__(256, 3) void k_main_mfma(
    const uint4* __restrict__ xf, const uint4* __restrict__ w0f,
    const uint4* __restrict__ w1f, const uint4* __restrict__ w2f,
    const float* __restrict__ zadj, const float* __restrict__ zadjT,
    const float* __restrict__ B0, const float* __restrict__ B1,
    const float* __restrict__ B2, const float* __restrict__ W3,
    const float* __restrict__ B3, float* __restrict__ outT) {
    const int bh = blockIdx.x;              // b-half (256 b's)
    const int c = blockIdx.y, sg = blockIdx.z;
    const int tid = threadIdx.x;
    const int wave = tid >> 6, lane = tid & 63;
    const int quad = lane >> 4;
    const int btbase = bh * 16 + wave * 4;  // 16-wide b-tiles

    // ---- hoisted channel weights
    V8 a0[2][2];                             // [Mt][ks]
#pragma unroll
    for (int Mt = 0; Mt < 2; ++Mt)
#pragma unroll
        for (int ks = 0; ks < 2; ++ks)
            a0[Mt][ks].u = w0f[(size_t)(c * 4 + Mt * 2 + ks) * 64 + lane];
    V8 a1[2], a2[2];                         // [Mt], permuted-K
#pragma unroll
    for (int Mt = 0; Mt < 2; ++Mt) {
        a1[Mt].u = w1f[(size_t)(c * 2 + Mt) * 64 + lane];
        a2[Mt].u = w2f[(size_t)(c * 2 + Mt) * 64 + lane];
    }
    // ---- hoisted x fragments (s-invariant)
    V8 xv[4][2];                             // [Nt][ks]
#pragma unroll
    for (int Nt = 0; Nt < 4; ++Nt)
#pragma unroll
        for (int ks = 0; ks < 2; ++ks)
            xv[Nt][ks].u = xf[(size_t)((btbase + Nt) * 2 + ks) * 64 + lane];
    // ---- biases / w3 (per-lane rows o = Mt*16 + quad*4 + r)
    f32x4 b0v[2], b1v[2], b2v[2], w3v[2];
#pragma unroll
    for (int Mt = 0; Mt < 2; ++Mt) {
        int off = c * 32 + Mt * 16 + quad * 4;
        b0v[Mt] = *(const f32x4*)(B0 + off);
        b1v[Mt] = *(const f32x4*)(B1 + off);
        b2v[Mt] = *(const f32x4*)(B2 + off);
        w3v[Mt] = *(const f32x4*)(W3 + off);
    }
    const float b3v = B3[c];

#pragma unroll 1
    for (int it = 0; it < 4; ++it) {
        const int s = sg * 4 + it;
        // ---- z (diag) for k = ks*32 + quad*8 + j, as f16 pairs
        f16x2 zvh[2][4];
        if (ZT) {
            const f32x4* ztp = (const f32x4*)(zadjT + (size_t)s * 4096 + c * 64);
            f32x4 zq[4];
            zq[0] = ztp[quad * 2];
            zq[1] = ztp[quad * 2 + 1];
            zq[2] = ztp[8 + quad * 2];
            zq[3] = ztp[8 + quad * 2 + 1];
#pragma unroll
            for (int ks = 0; ks < 2; ++ks)
#pragma unroll
                for (int t = 0; t < 4; ++t) {
                    const f32x4& v = zq[ks * 2 + (t >> 1)];
                    zvh[ks][t] = pkrtz(v[(t & 1) * 2], v[(t & 1) * 2 + 1]);
                }
        } else {
#pragma unroll
            for (int ks = 0; ks < 2; ++ks) {
                const float* zp = zadj + (size_t)s * 4096 + (ks * 32 + quad * 8) * 64 + c;
                float zv[8];
#pragma unroll
                for (int j = 0; j < 8; ++j) zv[j] = zp[j * 64];
#pragma unroll
                for (int t = 0; t < 4; ++t)
                    zvh[ks][t] = pkrtz(zv[2 * t], zv[2 * t + 1]);
            }
        }
        // ---- scale layer-0 A by z (A[m][k] *= z[k])
        V8 a0s[2][2];
#pragma unroll
        for (int Mt = 0; Mt < 2; ++Mt)
#pragma unroll
            for (int ks = 0; ks < 2; ++ks)
#pragma unroll
                for (int t = 0; t < 4; ++t)
                    a0s[Mt][ks].h2[t] = a0[Mt][ks].h2[t] * zvh[ks][t];

        float red[4];
#pragma unroll
        for (int Nt = 0; Nt < 4; ++Nt) {
            // ---------- layer 0 ----------
            f32x4 acc0[2] = {b0v[0], b0v[1]};
#pragma unroll
            for (int ks = 0; ks < 2; ++ks)
#pragma unroll
                for (int Mt = 0; Mt < 2; ++Mt)
                    acc0[Mt] = __builtin_amdgcn_mfma_f32_16x16x32_f16(
                        a0s[Mt][ks].v, xv[Nt][ks].v, acc0[Mt], 0, 0, 0);
            // ---------- transition 0->1 (pkrtz then packed relu) ----------
            V8 bb;
            bb.h2[0] = pkrtz(acc0[0][0], acc0[0][1]);
            bb.h2[1] = pkrtz(acc0[0][2], acc0[0][3]);
            bb.h2[2] = pkrtz(acc0[1][0], acc0[1][1]);
            bb.h2[3] = pkrtz(acc0[1][2], acc0[1][3]);
            bb.v = relu8(bb.v);
            // ---------- layer 1 ----------
            f32x4 acc1[2] = {b1v[0], b1v[1]};
#pragma unroll
            for (int Mt = 0; Mt < 2; ++Mt)
                acc1[Mt] = __builtin_amdgcn_mfma_f32_16x16x32_f16(
                    a1[Mt].v, bb.v, acc1[Mt], 0, 0, 0);
            // ---------- transition 1->2 ----------
            V8 cc;
            cc.h2[0] = pkrtz(acc1[0][0], acc1[0][1]);
            cc.h2[1] = pkrtz(acc1[0][2], acc1[0][3]);
            cc.h2[2] = pkrtz(acc1[1][0], acc1[1][1]);
            cc.h2[3] = pkrtz(acc1[1][2], acc1[1][3]);
            cc.v = relu8(cc.v);
            // ---------- layer 2 ----------
            f32x4 acc2[2] = {b2v[0], b2v[1]};
#pragma unroll
            for (int Mt = 0; Mt < 2; ++Mt)
                acc2[Mt] = __builtin_amdgcn_mfma_f32_16x16x32_f16(
                    a2[Mt].v, cc.v, acc2[Mt], 0, 0, 0);
            // ---------- layer 3 partial: relu(acc2) . w3 ----------
            float p = 0.0f;
#pragma unroll
            for (int Mt = 0; Mt < 2; ++Mt)
#pragma unroll
                for (int r = 0; r < 4; ++r)
                    p = fmaf(w3v[Mt][r], fmaxf(acc2[Mt][r], 0.0f), p);
            p += __shfl_xor(p, 16, 64);
            p += __shfl_xor(p, 32, 64);
            red[Nt] = p;
        }
        float outv = (quad & 2) ? ((quad & 1) ? red[3] : red[2])
                                : ((quad & 1) ? red[1] : red[0]);
        outv += b3v;
        outT[((size_t)s * 64 + c) * 512 + bh * 256 + tid] = outv;
    }
}

// ---------------------------------------------------------------------------
// Fallback VALU kernel (round-2 proven path).
// ---------------------------------------------------------------------------
__global__ __launch_bounds__(256, 3) void k_main_valu(
    const float* __restrict__ xsrc, const float* __restrict__ zadj,
    const float* __restrict__ W0, const float* __restrict__ B0,
    const float* __restrict__ W1, const float* __restrict__ B1,
    const float* __restrict__ W2, const float* __restrict__ B2,
    const float* __restrict__ W3, const float* __restrict__ B3,
    float* __restrict__ outp, int o_sS, int o_cS, int o_bS) {
    const int c = blockIdx.x;
    const int s = blockIdx.y;
    const int lane = threadIdx.x & 63;
    const int wave = threadIdx.x >> 6;

    const float* w0c = W0 + c * 2048;
    const float* w1c = W1 + c * 1024;
    const float* w2c = W2 + c * 1024;
    const float* w3c = W3 + c * 32;
    const float* b0c = B0 + c * 32;
    const float* b1c = B1 + c * 32;
    const float* b2c = B2 + c * 32;
    const float b3v = B3[c];
    const float* zc = zadj + s * 4096 + c;

#pragma unroll 1
    for (int bc = 0; bc < 2; ++bc) {
        const int b = wave * 128 + bc * 64 + lane;
        float h1[32], h2[32];
#pragma unroll
        for (int o = 0; o < 32; ++o) h1[o] = b0c[o];
#pragma unroll 8
        for (int i = 0; i < 64; ++i) {
            float hi = zc[i * 64] * xsrc[b * 64 + i];
#pragma unroll
            for (int o = 0; o < 32; ++o) h1[o] = fmaf(w0c[o * 64 + i], hi, h1[o]);
        }
#pragma unroll
        for (int o = 0; o < 32; ++o) { h1[o] = fmaxf(h1[o], 0.0f); h2[o] = b1c[o]; }
#pragma unroll 8
        for (int j = 0; j < 32; ++j) {
            float v = h1[j];
#pragma unroll
            for (int o = 0; o < 32; ++o) h2[o] = fmaf(w1c[o * 32 + j], v, h2[o]);
        }
#pragma unroll
        for (int o = 0; o < 32; ++o) { h2[o] = fmaxf(h2[o], 0.0f); h1[o] = b2c[o]; }
#pragma unroll 8
        for (int j = 0; j < 32; ++j) {
            float v = h2[j];
#pragma unroll
            for (int o = 0; o < 32; ++o) h1[o] = fmaf(w2c[o * 32 + j], v, h1[o]);
        }
        float a = b3v;
#pragma unroll
        for (int j = 0; j < 32; ++j) a = fmaf(w3c[j], fmaxf(h1[j], 0.0f), a);
        outp[s * o_sS + c * o_cS + b * o_bS] = a;
    }
}

// ---------------------------------------------------------------------------
// k_outT: transpose outT (s,c,b) -> out (b,s,c). dwordx4 global both sides.
// ---------------------------------------------------------------------------
__global__ __launch_bounds__(256) void k_outT(const float* __restrict__ outT,
                                              float* __restrict__ out) {
    __shared__ float tile[64 * 65];
    const int bt = blockIdx.x;   // 8 b-tiles
    const int s = blockIdx.y;    // 64
    const int tid = threadIdx.x;
    const int r16 = tid >> 4, q4 = (tid & 15) * 4;
#pragma unroll
    for (int rep = 0; rep < 4; ++rep) {
        int crow = rep * 16 + r16;
        f32x4 v = *(const f32x4*)&outT[(s * 64 + crow) * 512 + bt * 64 + q4];
#pragma unroll
        for (int i = 0; i < 4; ++i) tile[crow * 65 + q4 + i] = v[i];
    }
    __syncthreads();
#pragma unroll
    for (int rep = 0; rep < 4; ++rep) {
        int brow = rep * 16 + r16;
        f32x4 v;
#pragma unroll
        for (int i = 0; i < 4; ++i) v[i] = tile[(q4 + i) * 65 + brow];
        *(f32x4*)&out[(bt * 64 + brow) * 4096 + s * 64 + q4] = v;
    }
}

extern "C" void kernel_launch(void* const* d_in, const int* in_sizes, int n_in,
                              void* d_out, int out_size, void* d_ws, size_t ws_size,
                              hipStream_t stream) {
    const float* x  = (const float*)d_in[0];
    const float* z  = (const float*)d_in[1];
    const float* W0 = (const float*)d_in[2];
    const float* B0 = (const float*)d_in[3];
    const float* W1 = (const float*)d_in[4];
    const float* B1 = (const float*)d_in[5];
    const float* W2 = (const float*)d_in[6];
    const float* B2 = (const float*)d_in[7];
    const float* W3 = (const float*)d_in[8];
    const float* B3 = (const float*)d_in[9];

    float* out  = (float*)d_out;
    float* zadj = out + ZADJ_OFF;

    // workspace: outT | xf | w0f | w1f | w2f | zadjT
    const size_t OT_B  = (size_t)S * D * BSZ * sizeof(float); // 8388608
    const size_t XF_B  = 4096 * 16;                           // 65536
    const size_t W0F_B = (size_t)64 * 4 * 64 * 16;            // 262144
    const size_t W1F_B = (size_t)64 * 2 * 64 * 16;            // 131072
    const size_t W2F_B = W1F_B;
    const size_t ZT_B  = (size_t)S * 4096 * sizeof(float);    // 1048576
    const size_t FRAG_END = OT_B + XF_B + W0F_B + W1F_B + W2F_B;
    const bool has_oT   = ws_size >= OT_B;
    const bool has_frag = ws_size >= FRAG_END;
    const bool has_zt   = ws_size >= FRAG_END + ZT_B;

    char* wsb = (char*)d_ws;
    float* outT  = (float*)wsb;
    uint4* xf    = (uint4*)(wsb + OT_B);
    uint4* w0f   = (uint4*)(wsb + OT_B + XF_B);
    uint4* w1f   = (uint4*)(wsb + OT_B + XF_B + W0F_B);
    uint4* w2f   = (uint4*)(wsb + OT_B + XF_B + W0F_B + W1F_B);
    float* zadjT = (float*)(wsb + FRAG_END);

    if (has_frag) {
        hipLaunchKernelGGL(k_zadjprep, dim3(320), dim3(256), 0, stream,
                           z, zadj, has_zt ? zadjT : (float*)nullptr,
                           x, W0, W1, W2, w0f, w1f, w2f, xf);
        if (has_zt)
            hipLaunchKernelGGL((k_main_mfma<true>), dim3(2, 64, 16), dim3(256),
                               0, stream, xf, w0f, w1f, w2f, zadj, zadjT,
                               B0, B1, B2, W3, B3, outT);
        else
            hipLaunchKernelGGL((k_main_mfma<false>), dim3(2, 64, 16), dim3(256),
                               0, stream, xf, w0f, w1f, w2f, zadj, zadjT,
                               B0, B1, B2, W3, B3, outT);
        hipLaunchKernelGGL(k_outT, dim3(8, S), dim3(256), 0, stream, outT, out);
    } else {
        hipLaunchKernelGGL(k_zadjprep, dim3(256), dim3(256), 0, stream,
                           z, zadj, (float*)nullptr, x, W0, W1, W2,
                           (uint4*)nullptr, (uint4*)nullptr, (uint4*)nullptr,
                           (uint4*)nullptr);
        float* op = has_oT ? outT : out;
        const int o_sS = has_oT ? (64 * 512) : 64;
        const int o_cS = has_oT ? 512 : 1;
        const int o_bS = has_oT ? 1 : 4096;
        hipLaunchKernelGGL(k_main_valu, dim3(D, S), dim3(256), 0, stream,
                           x, zadj, W0, B0, W1, B1, W2, B2, W3, B3,
                           op, o_sS, o_cS, o_bS);
        if (has_oT)
            hipLaunchKernelGGL(k_outT, dim3(8, S), dim3(256), 0, stream, outT, out);
    }
}